// Round 1
// baseline (3442.099 us; speedup 1.0000x reference)
//
#include <hip/hip_runtime.h>
#include <hip/hip_bf16.h>
#include <math.h>

#define B_ 2
#define L_ 4096
#define D_ 1024
#define H_ 4
#define DK_ 256
#define BL_ 8192
#define C_ 1024
#define NCH_ 128
#define GQP_c 128
#define NS_c 6
#define GIN_c 134
#define GH_c 134

// ---------------- helpers ----------------
__device__ __forceinline__ float block_sum256(float v, float* red) {
  int t = threadIdx.x;
  #pragma unroll
  for (int o = 32; o > 0; o >>= 1) v += __shfl_down(v, o, 64);
  __syncthreads();
  if ((t & 63) == 0) red[t >> 6] = v;
  __syncthreads();
  return red[0] + red[1] + red[2] + red[3];
}

// ---------------- generic f32 GEMM: C = A(M,K) @ B(K,N) (+bias) ----------------
// 128x128 tile, BK=16, 256 threads, 8x8 per thread.
__global__ __launch_bounds__(256) void gemm_f32(const float* __restrict__ A,
    const float* __restrict__ Bm, const float* __restrict__ bias,
    float* __restrict__ C, int M, int N, int K) {
  __shared__ float As[16][132];
  __shared__ float Bs[16][132];
  int tid = threadIdx.x;
  int tx = tid & 15, ty = tid >> 4;
  int rowBase = blockIdx.y * 128, colBase = blockIdx.x * 128;
  float acc[8][8];
  #pragma unroll
  for (int i = 0; i < 8; ++i)
    #pragma unroll
    for (int j = 0; j < 8; ++j) acc[i][j] = 0.f;

  for (int kt = 0; kt < K; kt += 16) {
    #pragma unroll
    for (int q2 = 0; q2 < 2; ++q2) {
      int fi = tid + (q2 << 8);
      int r = fi >> 2, kq = (fi & 3) << 2;
      float4 a4 = *(const float4*)(A + (size_t)(rowBase + r) * K + kt + kq);
      As[kq + 0][r] = a4.x; As[kq + 1][r] = a4.y;
      As[kq + 2][r] = a4.z; As[kq + 3][r] = a4.w;
      int kr = fi >> 5, cq = (fi & 31) << 2;
      float4 b4 = *(const float4*)(Bm + (size_t)(kt + kr) * N + colBase + cq);
      *(float4*)&Bs[kr][cq] = b4;
    }
    __syncthreads();
    #pragma unroll
    for (int k = 0; k < 16; ++k) {
      float4 a0 = *(float4*)&As[k][ty * 8];
      float4 a1 = *(float4*)&As[k][ty * 8 + 4];
      float4 b0 = *(float4*)&Bs[k][tx * 8];
      float4 b1 = *(float4*)&Bs[k][tx * 8 + 4];
      float av[8] = {a0.x, a0.y, a0.z, a0.w, a1.x, a1.y, a1.z, a1.w};
      float bv[8] = {b0.x, b0.y, b0.z, b0.w, b1.x, b1.y, b1.z, b1.w};
      #pragma unroll
      for (int i = 0; i < 8; ++i)
        #pragma unroll
        for (int j = 0; j < 8; ++j) acc[i][j] += av[i] * bv[j];
    }
    __syncthreads();
  }
  #pragma unroll
  for (int i = 0; i < 8; ++i) {
    size_t row = rowBase + ty * 8 + i;
    float vals[8];
    #pragma unroll
    for (int j = 0; j < 8; ++j) {
      float bs = bias ? bias[colBase + tx * 8 + j] : 0.f;
      vals[j] = acc[i][j] + bs;
    }
    float4 o0 = {vals[0], vals[1], vals[2], vals[3]};
    float4 o1 = {vals[4], vals[5], vals[6], vals[7]};
    *(float4*)(C + row * N + colBase + tx * 8) = o0;
    *(float4*)(C + row * N + colBase + tx * 8 + 4) = o1;
  }
}

// ---------------- depthwise causal conv (K=4) + SiLU ----------------
__global__ __launch_bounds__(256) void conv_silu(const float* __restrict__ in,
    const float* __restrict__ w, float* __restrict__ out) {
  int idx = blockIdx.x * 256 + threadIdx.x;
  int c = idx & (C_ - 1);
  int l = (idx >> 10) & (L_ - 1);
  float acc = 0.f;
  #pragma unroll
  for (int j = 0; j < 4; ++j) {
    int ll = l - 3 + j;
    if (ll >= 0) acc += w[(c << 2) + j] * in[idx + ((j - 3) << 10)];
  }
  out[idx] = acc / (1.f + expf(-acc));
}

// ---------------- beta = sigmoid(x @ Wb) ----------------
__global__ __launch_bounds__(256) void beta_kernel(const float* __restrict__ x,
    const float* __restrict__ Wb, float* __restrict__ beta) {
  int row = blockIdx.x;
  int t = threadIdx.x;
  int h = t >> 6, lane = t & 63;
  const float* xr = x + (size_t)row * D_;
  float acc = 0.f;
  for (int k = lane; k < D_; k += 64) acc += xr[k] * Wb[(k << 2) + h];
  #pragma unroll
  for (int o = 32; o > 0; o >>= 1) acc += __shfl_down(acc, o, 64);
  if (lane == 0) beta[(row << 2) + h] = 1.f / (1.f + expf(-acc));
}

// ---------------- l2norm q,k; v*beta; kb; transpose BLHD -> BHLD ----------------
__global__ __launch_bounds__(256) void precompute(const float* __restrict__ q,
    const float* __restrict__ k, const float* __restrict__ v,
    const float* __restrict__ beta,
    float* __restrict__ qn, float* __restrict__ kn,
    float* __restrict__ vb, float* __restrict__ kb) {
  __shared__ float red[4];
  int bid = blockIdx.x;  // ((b*H + h)*L + l)
  int t = threadIdx.x;
  int b = bid >> 14;
  int h = (bid >> 12) & 3;
  int l = bid & (L_ - 1);
  size_t in_off = (((size_t)(b * L_ + l)) << 10) + (h << 8) + t;
  float qv = q[in_off], kv = k[in_off], vv = v[in_off];
  float sq = block_sum256(qv * qv, red);
  float sk = block_sum256(kv * kv, red);
  float rq = rsqrtf(sq + 1e-6f);
  float rk = rsqrtf(sk + 1e-6f);
  float bt = beta[((b * L_ + l) << 2) + h];
  size_t oo = ((size_t)bid << 8) + t;
  float knv = kv * rk;
  qn[oo] = qv * rq;
  kn[oo] = knv;
  vb[oo] = vv * bt;
  kb[oo] = knv * bt;
}

// ---------------- per-chunk: inv (forward substitution, bf16-rounded) + attn ----------------
__global__ __launch_bounds__(256) void inv_attn(const float* __restrict__ qn,
    const float* __restrict__ kn, const float* __restrict__ kb,
    float* __restrict__ invb, float* __restrict__ attb) {
  __shared__ float kn_s[32][257];
  __shared__ float inv_s[32][33];
  int ci = blockIdx.x;
  int t = threadIdx.x;
  size_t base = ((size_t)ci) << 13;  // chunk rows contiguous in BHLD
  for (int e = t; e < 8192; e += 256) kn_s[e >> 8][e & 255] = kn[base + e];
  __syncthreads();
  #pragma unroll
  for (int p = 0; p < 4; ++p) {
    int e = t + (p << 8);
    int i = e >> 5, j = e & 31;
    const float* kbi = kb + base + (i << 8);
    const float* qni = qn + base + (i << 8);
    float am = 0.f, aa = 0.f;
    for (int kk = 0; kk < 256; ++kk) {
      float knv = kn_s[j][kk];
      am += kbi[kk] * knv;
      aa += qni[kk] * knv;
    }
    inv_s[i][j] = (j < i) ? -am : 0.f;
    attb[((size_t)ci << 10) + e] = (j <= i) ? aa : 0.f;
  }
  __syncthreads();
  for (int i = 1; i < 32; ++i) {
    float upd = 0.f;
    if (t < i) {
      for (int kk = t + 1; kk < i; ++kk) upd += inv_s[i][kk] * inv_s[kk][t];
    }
    __syncthreads();
    if (t < i) inv_s[i][t] += upd;
    __syncthreads();
  }
  #pragma unroll
  for (int p = 0; p < 4; ++p) {
    int e = t + (p << 8);
    int i = e >> 5, j = e & 31;
    float val = inv_s[i][j] + (i == j ? 1.f : 0.f);
    val = __bfloat162float(__float2bfloat16(val));  // reference's bf16 round-trip
    invb[((size_t)ci << 10) + e] = val;
  }
}

// ---------------- u = inv@vb (in place), w = inv@kb (in place) ----------------
__global__ __launch_bounds__(256) void uw_kernel(const float* __restrict__ invb,
    float* __restrict__ vb_u, float* __restrict__ kb_w) {
  __shared__ float inv_s[32][33];
  __shared__ float tile[32][260];
  int ci = blockIdx.x, t = threadIdx.x;
  size_t base = ((size_t)ci) << 13;
  for (int e = t; e < 1024; e += 256) inv_s[e >> 5][e & 31] = invb[((size_t)ci << 10) + e];
  float* ptrs[2] = {vb_u, kb_w};
  for (int ph = 0; ph < 2; ++ph) {
    float* src = ptrs[ph];
    __syncthreads();
    for (int f = t; f < 2048; f += 256) {
      int e = f << 2;
      *(float4*)&tile[e >> 8][e & 255] = *(const float4*)(src + base + e);
    }
    __syncthreads();
    int c4 = (t & 63) << 2;
    int ig = t >> 6;
    float4 acc[8];
    #pragma unroll
    for (int ii = 0; ii < 8; ++ii) acc[ii] = make_float4(0.f, 0.f, 0.f, 0.f);
    for (int j = 0; j < 32; ++j) {
      float4 v4 = *(const float4*)&tile[j][c4];
      #pragma unroll
      for (int ii = 0; ii < 8; ++ii) {
        float iv = inv_s[(ig << 3) + ii][j];
        acc[ii].x += iv * v4.x; acc[ii].y += iv * v4.y;
        acc[ii].z += iv * v4.z; acc[ii].w += iv * v4.w;
      }
    }
    #pragma unroll
    for (int ii = 0; ii < 8; ++ii) {
      int i = (ig << 3) + ii;
      *(float4*)(src + base + (i << 8) + c4) = acc[ii];
    }
  }
}

// ---------------- sequential chunk scan; S columns split across blocks ----------------
// grid = 8 bh * 32 col-slices (8 cols each) = 256 blocks
__global__ __launch_bounds__(256) void scan_kernel(const float* __restrict__ qn,
    const float* __restrict__ kn, const float* __restrict__ u,
    const float* __restrict__ w, const float* __restrict__ attb,
    float* __restrict__ dout) {
  __shared__ float S[256][8];
  __shared__ float buf[32][257];
  __shared__ float ut[32][8];
  __shared__ float at[32][32];
  int t = threadIdx.x;
  int bh = blockIdx.x >> 5;
  int cb = blockIdx.x & 31;
  int cbo = cb << 3;
  for (int e = t; e < 2048; e += 256) ((float*)S)[e] = 0.f;
  int r2 = t >> 1, cg = t & 1;
  for (int nc = 0; nc < NCH_; ++nc) {
    int ci = (bh << 7) + nc;
    size_t base = ((size_t)ci) << 13;
    const float* ap = attb + (((size_t)ci) << 10);
    for (int e = t; e < 1024; e += 256) ((float*)at)[e] = ap[e];
    for (int e = t; e < 8192; e += 256) buf[e >> 8][e & 255] = w[base + e];
    __syncthreads();
    if (t < 64) {  // ut = u - w @ S
      float4 acc = *(const float4*)(u + base + (r2 << 8) + cbo + (cg << 2));
      for (int kk = 0; kk < 256; ++kk) {
        float wv = buf[r2][kk];
        const float4 s4 = *(const float4*)&S[kk][cg << 2];
        acc.x -= wv * s4.x; acc.y -= wv * s4.y; acc.z -= wv * s4.z; acc.w -= wv * s4.w;
      }
      *(float4*)&ut[r2][cg << 2] = acc;
    }
    __syncthreads();
    for (int e = t; e < 8192; e += 256) buf[e >> 8][e & 255] = qn[base + e];
    __syncthreads();
    if (t < 64) {  // o = q @ S + attn @ ut
      float4 acc = make_float4(0.f, 0.f, 0.f, 0.f);
      for (int kk = 0; kk < 256; ++kk) {
        float qv = buf[r2][kk];
        const float4 s4 = *(const float4*)&S[kk][cg << 2];
        acc.x += qv * s4.x; acc.y += qv * s4.y; acc.z += qv * s4.z; acc.w += qv * s4.w;
      }
      for (int j = 0; j <= r2; ++j) {
        float av = at[r2][j];
        const float4 u4 = *(const float4*)&ut[j][cg << 2];
        acc.x += av * u4.x; acc.y += av * u4.y; acc.z += av * u4.z; acc.w += av * u4.w;
      }
      *(float4*)(dout + base + (r2 << 8) + cbo + (cg << 2)) = acc;
    }
    __syncthreads();
    for (int e = t; e < 8192; e += 256) buf[e >> 8][e & 255] = kn[base + e];
    __syncthreads();
    {  // S += kn^T @ ut
      int dg = t >> 1;
      float4 inc0 = make_float4(0.f, 0.f, 0.f, 0.f);
      float4 inc1 = make_float4(0.f, 0.f, 0.f, 0.f);
      for (int r = 0; r < 32; ++r) {
        const float4 u4 = *(const float4*)&ut[r][cg << 2];
        float k0 = buf[r][dg];
        float k1 = buf[r][dg + 128];
        inc0.x += k0 * u4.x; inc0.y += k0 * u4.y; inc0.z += k0 * u4.z; inc0.w += k0 * u4.w;
        inc1.x += k1 * u4.x; inc1.y += k1 * u4.y; inc1.z += k1 * u4.z; inc1.w += k1 * u4.w;
      }
      float4 s0 = *(const float4*)&S[dg][cg << 2];
      s0.x += inc0.x; s0.y += inc0.y; s0.z += inc0.z; s0.w += inc0.w;
      *(float4*)&S[dg][cg << 2] = s0;
      float4 s1 = *(const float4*)&S[dg + 128][cg << 2];
      s1.x += inc1.x; s1.y += inc1.y; s1.z += inc1.z; s1.w += inc1.w;
      *(float4*)&S[dg + 128][cg << 2] = s1;
    }
    __syncthreads();
  }
}

// ---------------- FIR convs + gate MLP + softmax(floor) + fuse + RMSNorm ----------------
__global__ __launch_bounds__(256) void gate_kernel(const float* __restrict__ v,
    const float* __restrict__ delta, const float* __restrict__ qg,
    const float* __restrict__ fw0, const float* __restrict__ fw1,
    const float* __restrict__ fw2, const float* __restrict__ fw3,
    const float* __restrict__ Wf1, const float* __restrict__ bf1,
    const float* __restrict__ Wf2, const float* __restrict__ bf2,
    const float* __restrict__ ltm, const float* __restrict__ onw,
    float* __restrict__ o) {
  __shared__ float red[4];
  __shared__ float gin[GIN_c];
  __shared__ float hm[GH_c];
  __shared__ float lg[NS_c];
  __shared__ float pj[NS_c];
  int bl = blockIdx.x, t = threadIdx.x;
  int b = bl >> 12, l = bl & (L_ - 1);
  if (t < GQP_c) gin[t] = qg[((size_t)bl << 7) + t];
  __syncthreads();
  for (int h = 0; h < H_; ++h) {
    int c = (h << 8) + t;
    float st[6];
    size_t vcur = (((size_t)bl) << 10) + c;
    float v0 = v[vcur];
    st[0] = fw0[c] * v0;
    st[5] = v0;
    float a1 = 0.f;
    #pragma unroll
    for (int j = 0; j < 3; ++j) {
      int ll = l - 2 + j;
      if (ll >= 0) a1 += fw1[c * 3 + j] * v[(((size_t)(b * L_ + ll)) << 10) + c];
    }
    st[1] = a1;
    float a2 = 0.f;
    #pragma unroll
    for (int j = 0; j < 7; ++j) {
      int ll = l - 6 + j;
      if (ll >= 0) a2 += fw2[c * 7 + j] * v[(((size_t)(b * L_ + ll)) << 10) + c];
    }
    st[2] = a2;
    float a3 = 0.f;
    #pragma unroll
    for (int j = 0; j < 15; ++j) {
      int ll = l - 14 + j;
      if (ll >= 0) a3 += fw3[c * 15 + j] * v[(((size_t)(b * L_ + ll)) << 10) + c];
    }
    st[3] = a3;
    st[4] = delta[(((size_t)((b * H_ + h) * L_ + l)) << 8) + t];
    #pragma unroll
    for (int j = 0; j < 6; ++j) {
      float s = block_sum256(st[j], red);
      if (t == 0) gin[GQP_c + j] = s * (1.f / 256.f);
    }
    __syncthreads();
    if (t < GH_c) {
      float a = bf1[t];
      for (int i = 0; i < GIN_c; ++i) a += gin[i] * Wf1[i * GH_c + t];
      hm[t] = 0.5f * a * (1.f + erff(a * 0.70710678f));
    }
    __syncthreads();
    if (t < NS_c) {
      float a = bf2[t];
      for (int i = 0; i < GH_c; ++i) a += hm[i] * Wf2[i * NS_c + t];
      lg[t] = a / expf(ltm[h]);
    }
    __syncthreads();
    if (t == 0) {
      float m = lg[0];
      for (int j = 1; j < 6; ++j) m = fmaxf(m, lg[j]);
      float ssum = 0.f;
      float e[6];
      for (int j = 0; j < 6; ++j) { e[j] = expf(lg[j] - m); ssum += e[j]; }
      for (int j = 0; j < 6; ++j) pj[j] = e[j] / ssum * 0.88f + 0.02f;
    }
    __syncthreads();
    float fused = 0.f;
    #pragma unroll
    for (int j = 0; j < 6; ++j) fused += pj[j] * st[j];
    float ssq = block_sum256(fused * fused, red);
    float sc = rsqrtf(ssq * (1.f / 256.f) + 1e-5f);
    o[vcur] = fused * sc * onw[t];
    __syncthreads();
  }
}

// ---------------- launch ----------------
extern "C" void kernel_launch(void* const* d_in, const int* in_sizes, int n_in,
                              void* d_out, int out_size, void* d_ws, size_t ws_size,
                              hipStream_t stream) {
  const float* x   = (const float*)d_in[0];
  const float* Wq  = (const float*)d_in[1];
  const float* Wk  = (const float*)d_in[2];
  const float* Wv  = (const float*)d_in[3];
  const float* Wb  = (const float*)d_in[4];
  const float* cqw = (const float*)d_in[5];
  const float* ckw = (const float*)d_in[6];
  const float* cvw = (const float*)d_in[7];
  const float* fw0 = (const float*)d_in[8];
  const float* fw1 = (const float*)d_in[9];
  const float* fw2 = (const float*)d_in[10];
  const float* fw3 = (const float*)d_in[11];
  const float* Wqg = (const float*)d_in[12];
  const float* bqg = (const float*)d_in[13];
  const float* Wf1 = (const float*)d_in[14];
  const float* bf1 = (const float*)d_in[15];
  const float* Wf2 = (const float*)d_in[16];
  const float* bf2 = (const float*)d_in[17];
  const float* ltm = (const float*)d_in[18];
  const float* onw = (const float*)d_in[19];
  const float* Wo  = (const float*)d_in[20];
  float* out = (float*)d_out;
  float* ws = (float*)d_ws;

  const size_t BIG = (size_t)BL_ * C_;
  float* qpre = ws;                 // -> qn
  float* kpre = ws + BIG;           // -> kn
  float* vpre = ws + 2 * BIG;       // -> vb -> u
  float* qs   = ws + 3 * BIG;       // conv q -> delta_out
  float* ks   = ws + 4 * BIG;       // conv k -> o (gate output)
  float* vs   = ws + 5 * BIG;       // conv v (kept for FIR/v_direct)
  float* kbw  = ws + 6 * BIG;       // kb -> w
  float* invb = ws + 7 * BIG;       // 1024 chunks * 1024
  float* attb = invb + (size_t)1024 * 1024;
  float* beta = attb + (size_t)1024 * 1024;
  float* qg   = beta + (size_t)BL_ * H_;

  dim3 blk(256);
  gemm_f32<<<dim3(C_ / 128, BL_ / 128), blk, 0, stream>>>(x, Wq, nullptr, qpre, BL_, C_, D_);
  gemm_f32<<<dim3(C_ / 128, BL_ / 128), blk, 0, stream>>>(x, Wk, nullptr, kpre, BL_, C_, D_);
  gemm_f32<<<dim3(C_ / 128, BL_ / 128), blk, 0, stream>>>(x, Wv, nullptr, vpre, BL_, C_, D_);
  gemm_f32<<<dim3(GQP_c / 128, BL_ / 128), blk, 0, stream>>>(x, Wqg, bqg, qg, BL_, GQP_c, D_);
  beta_kernel<<<dim3(BL_), blk, 0, stream>>>(x, Wb, beta);
  conv_silu<<<dim3(BL_ * C_ / 256), blk, 0, stream>>>(qpre, cqw, qs);
  conv_silu<<<dim3(BL_ * C_ / 256), blk, 0, stream>>>(kpre, ckw, ks);
  conv_silu<<<dim3(BL_ * C_ / 256), blk, 0, stream>>>(vpre, cvw, vs);
  precompute<<<dim3(B_ * H_ * L_), blk, 0, stream>>>(qs, ks, vs, beta, qpre, kpre, vpre, kbw);
  inv_attn<<<dim3(1024), blk, 0, stream>>>(qpre, kpre, kbw, invb, attb);
  uw_kernel<<<dim3(1024), blk, 0, stream>>>(invb, vpre, kbw);
  scan_kernel<<<dim3(256), blk, 0, stream>>>(qpre, kpre, vpre, kbw, attb, qs);
  gate_kernel<<<dim3(BL_), blk, 0, stream>>>(vs, qs, qg, fw0, fw1, fw2, fw3,
                                             Wf1, bf1, Wf2, bf2, ltm, onw, ks);
  gemm_f32<<<dim3(D_ / 128, BL_ / 128), blk, 0, stream>>>(ks, Wo, nullptr, out, BL_, D_, C_);
}

// Round 2
// 2642.092 us; speedup vs baseline: 1.3028x; 1.3028x over previous
//
#include <hip/hip_runtime.h>
#include <hip/hip_bf16.h>
#include <math.h>

#define B_ 2
#define L_ 4096
#define D_ 1024
#define H_ 4
#define DK_ 256
#define BL_ 8192
#define C_ 1024
#define NCH_ 128
#define GQP_c 128
#define NS_c 6
#define GIN_c 134
#define GH_c 134

typedef __attribute__((ext_vector_type(8))) short short8;
typedef __attribute__((ext_vector_type(4))) float f32x4;

// ---------------- helpers ----------------
__device__ __forceinline__ float block_sum256(float v, float* red) {
  int t = threadIdx.x;
  #pragma unroll
  for (int o = 32; o > 0; o >>= 1) v += __shfl_down(v, o, 64);
  __syncthreads();
  if ((t & 63) == 0) red[t >> 6] = v;
  __syncthreads();
  return red[0] + red[1] + red[2] + red[3];
}

__device__ __forceinline__ unsigned short bf16bits(float f) {
  __hip_bfloat16 h = __float2bfloat16(f);
  return *(unsigned short*)&h;
}

__device__ __forceinline__ void gload_lds16(const void* g, void* l) {
  __builtin_amdgcn_global_load_lds(
      (const __attribute__((address_space(1))) void*)g,
      (__attribute__((address_space(3))) void*)l, 16, 0, 0);
}

// ---------------- f32 -> bf16 convert ----------------
__global__ __launch_bounds__(256) void f32_to_bf16_k(const float* __restrict__ in,
    __hip_bfloat16* __restrict__ out) {
  size_t i = ((size_t)blockIdx.x * 256 + threadIdx.x) << 2;
  float4 v = *(const float4*)(in + i);
  ushort4 o;
  o.x = bf16bits(v.x); o.y = bf16bits(v.y); o.z = bf16bits(v.z); o.w = bf16bits(v.w);
  *(ushort4*)((unsigned short*)out + i) = o;
}

// ---------------- transpose W(K,N) f32 -> WT(N,K) bf16 ----------------
__global__ __launch_bounds__(256) void transpose_bf16(const float* __restrict__ W,
    __hip_bfloat16* __restrict__ WT, int K, int N) {
  __shared__ float tile[32][33];
  int t = threadIdx.x;
  int r = t >> 3, c4 = (t & 7) << 2;
  int n0 = blockIdx.x << 5, k0 = blockIdx.y << 5;
  float4 v = *(const float4*)(W + (size_t)(k0 + r) * N + n0 + c4);
  tile[r][c4] = v.x; tile[r][c4 + 1] = v.y; tile[r][c4 + 2] = v.z; tile[r][c4 + 3] = v.w;
  __syncthreads();
  ushort4 o;
  o.x = bf16bits(tile[c4][r]);
  o.y = bf16bits(tile[c4 + 1][r]);
  o.z = bf16bits(tile[c4 + 2][r]);
  o.w = bf16bits(tile[c4 + 3][r]);
  *(ushort4*)((unsigned short*)WT + (size_t)(n0 + r) * K + k0 + c4) = o;
}

// ---------------- bf16 MFMA GEMM: C(M,N) f32 = A(M,K)bf16 @ BT(N,K)bf16^T ----------------
// 128x128 tile, BK=32, 256 thr = 4 waves (2x2), each wave 64x64 via 4x4 of 16x16x32.
// LDS layout: tile stored as 16B chunks in MFMA-frag read order -> ds_read_b128
// addresses are base + T*1024B + lane*16B (contiguous, conflict-free).
__global__ __launch_bounds__(256) void gemm_bf16(
    const __hip_bfloat16* __restrict__ A, const __hip_bfloat16* __restrict__ BT,
    const float* __restrict__ bias, float* __restrict__ C, int M, int N, int K) {
  __shared__ __align__(16) __hip_bfloat16 Asm[4096];
  __shared__ __align__(16) __hip_bfloat16 Bsm[4096];
  int tid = threadIdx.x;
  int lane = tid & 63, wave = tid >> 6;
  int wm = wave >> 1, wn = wave & 1;
  int rowBase = blockIdx.y * 128, colBase = blockIdx.x * 128;
  f32x4 acc[4][4];
  #pragma unroll
  for (int i = 0; i < 4; ++i)
    #pragma unroll
    for (int j = 0; j < 4; ++j) acc[i][j] = (f32x4){0.f, 0.f, 0.f, 0.f};

  for (int kt = 0; kt < K; kt += 32) {
    __syncthreads();
    #pragma unroll
    for (int it = 0; it < 2; ++it) {
      int s = tid + (it << 8);                 // chunk id 0..511
      int T = s >> 6, q = (s >> 4) & 3, m = s & 15;
      const __hip_bfloat16* ga = A + (size_t)(rowBase + T * 16 + m) * K + kt + q * 8;
      gload_lds16(ga, Asm + s * 8);
      const __hip_bfloat16* gb = BT + (size_t)(colBase + T * 16 + m) * K + kt + q * 8;
      gload_lds16(gb, Bsm + s * 8);
    }
    __syncthreads();
    short8 af[4], bfr[4];
    #pragma unroll
    for (int i = 0; i < 4; ++i) {
      af[i]  = *(const short8*)(Asm + ((wm * 4 + i) << 9) + lane * 8);
      bfr[i] = *(const short8*)(Bsm + ((wn * 4 + i) << 9) + lane * 8);
    }
    #pragma unroll
    for (int i = 0; i < 4; ++i)
      #pragma unroll
      for (int j = 0; j < 4; ++j)
        acc[i][j] = __builtin_amdgcn_mfma_f32_16x16x32_bf16(af[i], bfr[j], acc[i][j], 0, 0, 0);
  }
  int r0 = (lane >> 4) * 4, c0 = lane & 15;
  #pragma unroll
  for (int i = 0; i < 4; ++i) {
    int row = rowBase + (wm * 4 + i) * 16 + r0;
    #pragma unroll
    for (int j = 0; j < 4; ++j) {
      int col = colBase + (wn * 4 + j) * 16 + c0;
      float bs = bias ? bias[col] : 0.f;
      #pragma unroll
      for (int r = 0; r < 4; ++r)
        C[(size_t)(row + r) * N + col] = acc[i][j][r] + bs;
    }
  }
}

// ---------------- depthwise causal conv (K=4) + SiLU ----------------
__global__ __launch_bounds__(256) void conv_silu(const float* __restrict__ in,
    const float* __restrict__ w, float* __restrict__ out) {
  int idx = blockIdx.x * 256 + threadIdx.x;
  int c = idx & (C_ - 1);
  int l = (idx >> 10) & (L_ - 1);
  float acc = 0.f;
  #pragma unroll
  for (int j = 0; j < 4; ++j) {
    int ll = l - 3 + j;
    if (ll >= 0) acc += w[(c << 2) + j] * in[idx + ((j - 3) << 10)];
  }
  out[idx] = acc / (1.f + expf(-acc));
}

// ---------------- beta = sigmoid(x @ Wb) ----------------
__global__ __launch_bounds__(256) void beta_kernel(const float* __restrict__ x,
    const float* __restrict__ Wb, float* __restrict__ beta) {
  int row = blockIdx.x;
  int t = threadIdx.x;
  int h = t >> 6, lane = t & 63;
  const float* xr = x + (size_t)row * D_;
  float acc = 0.f;
  for (int k = lane; k < D_; k += 64) acc += xr[k] * Wb[(k << 2) + h];
  #pragma unroll
  for (int o = 32; o > 0; o >>= 1) acc += __shfl_down(acc, o, 64);
  if (lane == 0) beta[(row << 2) + h] = 1.f / (1.f + expf(-acc));
}

// ---------------- l2norm q,k; v*beta; kb; transpose BLHD -> BHLD ----------------
__global__ __launch_bounds__(256) void precompute(const float* __restrict__ q,
    const float* __restrict__ k, const float* __restrict__ v,
    const float* __restrict__ beta,
    float* __restrict__ qn, float* __restrict__ kn,
    float* __restrict__ vb, float* __restrict__ kb) {
  __shared__ float red[4];
  int bid = blockIdx.x;  // ((b*H + h)*L + l)
  int t = threadIdx.x;
  int b = bid >> 14;
  int h = (bid >> 12) & 3;
  int l = bid & (L_ - 1);
  size_t in_off = (((size_t)(b * L_ + l)) << 10) + (h << 8) + t;
  float qv = q[in_off], kv = k[in_off], vv = v[in_off];
  float sq = block_sum256(qv * qv, red);
  float sk = block_sum256(kv * kv, red);
  float rq = rsqrtf(sq + 1e-6f);
  float rk = rsqrtf(sk + 1e-6f);
  float bt = beta[((b * L_ + l) << 2) + h];
  size_t oo = ((size_t)bid << 8) + t;
  float knv = kv * rk;
  qn[oo] = qv * rq;
  kn[oo] = knv;
  vb[oo] = vv * bt;
  kb[oo] = knv * bt;
}

// ---------------- per-chunk: inv (forward substitution, bf16-rounded) + attn ----------------
__global__ __launch_bounds__(256) void inv_attn(const float* __restrict__ qn,
    const float* __restrict__ kn, const float* __restrict__ kb,
    float* __restrict__ invb, float* __restrict__ attb) {
  __shared__ float kn_s[32][257];
  __shared__ float inv_s[32][33];
  int ci = blockIdx.x;
  int t = threadIdx.x;
  size_t base = ((size_t)ci) << 13;
  for (int e = t; e < 8192; e += 256) kn_s[e >> 8][e & 255] = kn[base + e];
  __syncthreads();
  #pragma unroll
  for (int p = 0; p < 4; ++p) {
    int e = t + (p << 8);
    int i = e >> 5, j = e & 31;
    const float* kbi = kb + base + (i << 8);
    const float* qni = qn + base + (i << 8);
    float am = 0.f, aa = 0.f;
    for (int kk = 0; kk < 256; ++kk) {
      float knv = kn_s[j][kk];
      am += kbi[kk] * knv;
      aa += qni[kk] * knv;
    }
    inv_s[i][j] = (j < i) ? -am : 0.f;
    attb[((size_t)ci << 10) + e] = (j <= i) ? aa : 0.f;
  }
  __syncthreads();
  for (int i = 1; i < 32; ++i) {
    float upd = 0.f;
    if (t < i) {
      for (int kk = t + 1; kk < i; ++kk) upd += inv_s[i][kk] * inv_s[kk][t];
    }
    __syncthreads();
    if (t < i) inv_s[i][t] += upd;
    __syncthreads();
  }
  #pragma unroll
  for (int p = 0; p < 4; ++p) {
    int e = t + (p << 8);
    int i = e >> 5, j = e & 31;
    float val = inv_s[i][j] + (i == j ? 1.f : 0.f);
    val = __bfloat162float(__float2bfloat16(val));
    invb[((size_t)ci << 10) + e] = val;
  }
}

// ---------------- u = inv@vb (in place), w = inv@kb (in place) ----------------
__global__ __launch_bounds__(256) void uw_kernel(const float* __restrict__ invb,
    float* __restrict__ vb_u, float* __restrict__ kb_w) {
  __shared__ float inv_s[32][33];
  __shared__ float tile[32][260];
  int ci = blockIdx.x, t = threadIdx.x;
  size_t base = ((size_t)ci) << 13;
  for (int e = t; e < 1024; e += 256) inv_s[e >> 5][e & 31] = invb[((size_t)ci << 10) + e];
  float* ptrs[2] = {vb_u, kb_w};
  for (int ph = 0; ph < 2; ++ph) {
    float* src = ptrs[ph];
    __syncthreads();
    for (int f = t; f < 2048; f += 256) {
      int e = f << 2;
      *(float4*)&tile[e >> 8][e & 255] = *(const float4*)(src + base + e);
    }
    __syncthreads();
    int c4 = (t & 63) << 2;
    int ig = t >> 6;
    float4 acc[8];
    #pragma unroll
    for (int ii = 0; ii < 8; ++ii) acc[ii] = make_float4(0.f, 0.f, 0.f, 0.f);
    for (int j = 0; j < 32; ++j) {
      float4 v4 = *(const float4*)&tile[j][c4];
      #pragma unroll
      for (int ii = 0; ii < 8; ++ii) {
        float iv = inv_s[(ig << 3) + ii][j];
        acc[ii].x += iv * v4.x; acc[ii].y += iv * v4.y;
        acc[ii].z += iv * v4.z; acc[ii].w += iv * v4.w;
      }
    }
    #pragma unroll
    for (int ii = 0; ii < 8; ++ii) {
      int i = (ig << 3) + ii;
      *(float4*)(src + base + (i << 8) + c4) = acc[ii];
    }
  }
}

// ---------------- sequential chunk scan; S columns split across blocks ----------------
__global__ __launch_bounds__(256) void scan_kernel(const float* __restrict__ qn,
    const float* __restrict__ kn, const float* __restrict__ u,
    const float* __restrict__ w, const float* __restrict__ attb,
    float* __restrict__ dout) {
  __shared__ float S[256][8];
  __shared__ float buf[32][257];
  __shared__ float ut[32][8];
  __shared__ float at[32][32];
  int t = threadIdx.x;
  int bh = blockIdx.x >> 5;
  int cb = blockIdx.x & 31;
  int cbo = cb << 3;
  for (int e = t; e < 2048; e += 256) ((float*)S)[e] = 0.f;
  int r2 = t >> 1, cg = t & 1;
  for (int nc = 0; nc < NCH_; ++nc) {
    int ci = (bh << 7) + nc;
    size_t base = ((size_t)ci) << 13;
    const float* ap = attb + (((size_t)ci) << 10);
    for (int e = t; e < 1024; e += 256) ((float*)at)[e] = ap[e];
    for (int e = t; e < 8192; e += 256) buf[e >> 8][e & 255] = w[base + e];
    __syncthreads();
    if (t < 64) {
      float4 acc = *(const float4*)(u + base + (r2 << 8) + cbo + (cg << 2));
      for (int kk = 0; kk < 256; ++kk) {
        float wv = buf[r2][kk];
        const float4 s4 = *(const float4*)&S[kk][cg << 2];
        acc.x -= wv * s4.x; acc.y -= wv * s4.y; acc.z -= wv * s4.z; acc.w -= wv * s4.w;
      }
      *(float4*)&ut[r2][cg << 2] = acc;
    }
    __syncthreads();
    for (int e = t; e < 8192; e += 256) buf[e >> 8][e & 255] = qn[base + e];
    __syncthreads();
    if (t < 64) {
      float4 acc = make_float4(0.f, 0.f, 0.f, 0.f);
      for (int kk = 0; kk < 256; ++kk) {
        float qv = buf[r2][kk];
        const float4 s4 = *(const float4*)&S[kk][cg << 2];
        acc.x += qv * s4.x; acc.y += qv * s4.y; acc.z += qv * s4.z; acc.w += qv * s4.w;
      }
      for (int j = 0; j <= r2; ++j) {
        float av = at[r2][j];
        const float4 u4 = *(const float4*)&ut[j][cg << 2];
        acc.x += av * u4.x; acc.y += av * u4.y; acc.z += av * u4.z; acc.w += av * u4.w;
      }
      *(float4*)(dout + base + (r2 << 8) + cbo + (cg << 2)) = acc;
    }
    __syncthreads();
    for (int e = t; e < 8192; e += 256) buf[e >> 8][e & 255] = kn[base + e];
    __syncthreads();
    {
      int dg = t >> 1;
      float4 inc0 = make_float4(0.f, 0.f, 0.f, 0.f);
      float4 inc1 = make_float4(0.f, 0.f, 0.f, 0.f);
      for (int r = 0; r < 32; ++r) {
        const float4 u4 = *(const float4*)&ut[r][cg << 2];
        float k0 = buf[r][dg];
        float k1 = buf[r][dg + 128];
        inc0.x += k0 * u4.x; inc0.y += k0 * u4.y; inc0.z += k0 * u4.z; inc0.w += k0 * u4.w;
        inc1.x += k1 * u4.x; inc1.y += k1 * u4.y; inc1.z += k1 * u4.z; inc1.w += k1 * u4.w;
      }
      float4 s0 = *(const float4*)&S[dg][cg << 2];
      s0.x += inc0.x; s0.y += inc0.y; s0.z += inc0.z; s0.w += inc0.w;
      *(float4*)&S[dg][cg << 2] = s0;
      float4 s1 = *(const float4*)&S[dg + 128][cg << 2];
      s1.x += inc1.x; s1.y += inc1.y; s1.z += inc1.z; s1.w += inc1.w;
      *(float4*)&S[dg + 128][cg << 2] = s1;
    }
    __syncthreads();
  }
}

// ---------------- FIR convs + gate MLP + softmax(floor) + fuse + RMSNorm ----------------
__global__ __launch_bounds__(256) void gate_kernel(const float* __restrict__ v,
    const float* __restrict__ delta, const float* __restrict__ qg,
    const float* __restrict__ fw0, const float* __restrict__ fw1,
    const float* __restrict__ fw2, const float* __restrict__ fw3,
    const float* __restrict__ Wf1, const float* __restrict__ bf1,
    const float* __restrict__ Wf2, const float* __restrict__ bf2,
    const float* __restrict__ ltm, const float* __restrict__ onw,
    float* __restrict__ o, __hip_bfloat16* __restrict__ obf) {
  __shared__ float red[4];
  __shared__ float gin[GIN_c];
  __shared__ float hm[GH_c];
  __shared__ float lg[NS_c];
  __shared__ float pj[NS_c];
  int bl = blockIdx.x, t = threadIdx.x;
  int b = bl >> 12, l = bl & (L_ - 1);
  if (t < GQP_c) gin[t] = qg[((size_t)bl << 7) + t];
  __syncthreads();
  for (int h = 0; h < H_; ++h) {
    int c = (h << 8) + t;
    float st[6];
    size_t vcur = (((size_t)bl) << 10) + c;
    float v0 = v[vcur];
    st[0] = fw0[c] * v0;
    st[5] = v0;
    float a1 = 0.f;
    #pragma unroll
    for (int j = 0; j < 3; ++j) {
      int ll = l - 2 + j;
      if (ll >= 0) a1 += fw1[c * 3 + j] * v[(((size_t)(b * L_ + ll)) << 10) + c];
    }
    st[1] = a1;
    float a2 = 0.f;
    #pragma unroll
    for (int j = 0; j < 7; ++j) {
      int ll = l - 6 + j;
      if (ll >= 0) a2 += fw2[c * 7 + j] * v[(((size_t)(b * L_ + ll)) << 10) + c];
    }
    st[2] = a2;
    float a3 = 0.f;
    #pragma unroll
    for (int j = 0; j < 15; ++j) {
      int ll = l - 14 + j;
      if (ll >= 0) a3 += fw3[c * 15 + j] * v[(((size_t)(b * L_ + ll)) << 10) + c];
    }
    st[3] = a3;
    st[4] = delta[(((size_t)((b * H_ + h) * L_ + l)) << 8) + t];
    #pragma unroll
    for (int j = 0; j < 6; ++j) {
      float s = block_sum256(st[j], red);
      if (t == 0) gin[GQP_c + j] = s * (1.f / 256.f);
    }
    __syncthreads();
    if (t < GH_c) {
      float a = bf1[t];
      for (int i = 0; i < GIN_c; ++i) a += gin[i] * Wf1[i * GH_c + t];
      hm[t] = 0.5f * a * (1.f + erff(a * 0.70710678f));
    }
    __syncthreads();
    if (t < NS_c) {
      float a = bf2[t];
      for (int i = 0; i < GH_c; ++i) a += hm[i] * Wf2[i * NS_c + t];
      lg[t] = a / expf(ltm[h]);
    }
    __syncthreads();
    if (t == 0) {
      float m = lg[0];
      for (int j = 1; j < 6; ++j) m = fmaxf(m, lg[j]);
      float ssum = 0.f;
      float e[6];
      for (int j = 0; j < 6; ++j) { e[j] = expf(lg[j] - m); ssum += e[j]; }
      for (int j = 0; j < 6; ++j) pj[j] = e[j] / ssum * 0.88f + 0.02f;
    }
    __syncthreads();
    float fused = 0.f;
    #pragma unroll
    for (int j = 0; j < 6; ++j) fused += pj[j] * st[j];
    float ssq = block_sum256(fused * fused, red);
    float sc = rsqrtf(ssq * (1.f / 256.f) + 1e-5f);
    float ov = fused * sc * onw[t];
    o[vcur] = ov;
    obf[vcur] = __float2bfloat16(ov);
    __syncthreads();
  }
}

// ---------------- launch ----------------
extern "C" void kernel_launch(void* const* d_in, const int* in_sizes, int n_in,
                              void* d_out, int out_size, void* d_ws, size_t ws_size,
                              hipStream_t stream) {
  const float* x   = (const float*)d_in[0];
  const float* Wq  = (const float*)d_in[1];
  const float* Wk  = (const float*)d_in[2];
  const float* Wv  = (const float*)d_in[3];
  const float* Wb  = (const float*)d_in[4];
  const float* cqw = (const float*)d_in[5];
  const float* ckw = (const float*)d_in[6];
  const float* cvw = (const float*)d_in[7];
  const float* fw0 = (const float*)d_in[8];
  const float* fw1 = (const float*)d_in[9];
  const float* fw2 = (const float*)d_in[10];
  const float* fw3 = (const float*)d_in[11];
  const float* Wqg = (const float*)d_in[12];
  const float* bqg = (const float*)d_in[13];
  const float* Wf1 = (const float*)d_in[14];
  const float* bf1 = (const float*)d_in[15];
  const float* Wf2 = (const float*)d_in[16];
  const float* bf2 = (const float*)d_in[17];
  const float* ltm = (const float*)d_in[18];
  const float* onw = (const float*)d_in[19];
  const float* Wo  = (const float*)d_in[20];
  float* out = (float*)d_out;
  float* ws = (float*)d_ws;

  const size_t BIG = (size_t)BL_ * C_;
  float* qpre = ws;                 // -> qn ; then gate_bf (bf16) at end
  float* kpre = ws + BIG;           // -> kn
  float* vpre = ws + 2 * BIG;       // -> vb -> u
  float* qs   = ws + 3 * BIG;       // x_bf early -> conv q -> delta_out
  float* ks   = ws + 4 * BIG;       // conv k -> o (gate output)
  float* vs   = ws + 5 * BIG;       // conv v (kept for FIR/v_direct)
  float* kbw  = ws + 6 * BIG;       // wT (bf16) early -> kb -> w -> woT (bf16)
  float* invb = ws + 7 * BIG;
  float* attb = invb + (size_t)1024 * 1024;
  float* beta = attb + (size_t)1024 * 1024;
  float* qg   = beta + (size_t)BL_ * H_;

  // bf16 aliases (lifetimes verified against f32 users of the same regions)
  __hip_bfloat16* x_bf  = (__hip_bfloat16*)qs;    // dead before conv writes qs
  __hip_bfloat16* wqT   = (__hip_bfloat16*)kbw;   // dead before precompute writes kb
  __hip_bfloat16* wkT   = wqT + (size_t)1024 * 1024;
  __hip_bfloat16* wvT   = wkT + (size_t)1024 * 1024;
  __hip_bfloat16* wqgT  = wvT + (size_t)1024 * 1024;
  __hip_bfloat16* woT   = (__hip_bfloat16*)kbw;   // written after scan consumes w
  __hip_bfloat16* gate_bf = (__hip_bfloat16*)qpre; // written after scan consumes qn

  dim3 blk(256);
  // --- bf16 conversions / weight transposes ---
  f32_to_bf16_k<<<dim3(BL_ * D_ / 1024), blk, 0, stream>>>(x, x_bf);
  transpose_bf16<<<dim3(32, 32), blk, 0, stream>>>(Wq, wqT, D_, C_);
  transpose_bf16<<<dim3(32, 32), blk, 0, stream>>>(Wk, wkT, D_, C_);
  transpose_bf16<<<dim3(32, 32), blk, 0, stream>>>(Wv, wvT, D_, C_);
  transpose_bf16<<<dim3(4, 32), blk, 0, stream>>>(Wqg, wqgT, D_, GQP_c);
  // --- MFMA projections ---
  gemm_bf16<<<dim3(8, 64), blk, 0, stream>>>(x_bf, wqT, nullptr, qpre, BL_, C_, D_);
  gemm_bf16<<<dim3(8, 64), blk, 0, stream>>>(x_bf, wkT, nullptr, kpre, BL_, C_, D_);
  gemm_bf16<<<dim3(8, 64), blk, 0, stream>>>(x_bf, wvT, nullptr, vpre, BL_, C_, D_);
  gemm_bf16<<<dim3(1, 64), blk, 0, stream>>>(x_bf, wqgT, bqg, qg, BL_, GQP_c, D_);
  beta_kernel<<<dim3(BL_), blk, 0, stream>>>(x, Wb, beta);
  // --- conv + delta pipeline (f32, unchanged) ---
  conv_silu<<<dim3(BL_ * C_ / 256), blk, 0, stream>>>(qpre, cqw, qs);
  conv_silu<<<dim3(BL_ * C_ / 256), blk, 0, stream>>>(kpre, ckw, ks);
  conv_silu<<<dim3(BL_ * C_ / 256), blk, 0, stream>>>(vpre, cvw, vs);
  precompute<<<dim3(B_ * H_ * L_), blk, 0, stream>>>(qs, ks, vs, beta, qpre, kpre, vpre, kbw);
  inv_attn<<<dim3(1024), blk, 0, stream>>>(qpre, kpre, kbw, invb, attb);
  uw_kernel<<<dim3(1024), blk, 0, stream>>>(invb, vpre, kbw);
  scan_kernel<<<dim3(256), blk, 0, stream>>>(qpre, kpre, vpre, kbw, attb, qs);
  // --- output path ---
  transpose_bf16<<<dim3(32, 32), blk, 0, stream>>>(Wo, woT, C_, D_);
  gate_kernel<<<dim3(BL_), blk, 0, stream>>>(vs, qs, qg, fw0, fw1, fw2, fw3,
                                             Wf1, bf1, Wf2, bf2, ltm, onw, ks, gate_bf);
  gemm_bf16<<<dim3(8, 64), blk, 0, stream>>>(gate_bf, woT, nullptr, out, BL_, D_, C_);
}

// Round 4
// 1684.977 us; speedup vs baseline: 2.0428x; 1.5680x over previous
//
#include <hip/hip_runtime.h>
#include <hip/hip_bf16.h>
#include <math.h>

#define B_ 2
#define L_ 4096
#define D_ 1024
#define H_ 4
#define DK_ 256
#define BL_ 8192
#define C_ 1024
#define NCH_ 128
#define GQP_c 128
#define NS_c 6
#define GIN_c 134
#define GH_c 134

typedef __attribute__((ext_vector_type(8))) short short8;
typedef __attribute__((ext_vector_type(4))) float f32x4;

// ---------------- helpers ----------------
__device__ __forceinline__ float block_sum256(float v, float* red) {
  int t = threadIdx.x;
  #pragma unroll
  for (int o = 32; o > 0; o >>= 1) v += __shfl_down(v, o, 64);
  __syncthreads();
  if ((t & 63) == 0) red[t >> 6] = v;
  __syncthreads();
  return red[0] + red[1] + red[2] + red[3];
}

__device__ __forceinline__ unsigned short bf16bits(float f) {
  __hip_bfloat16 h = __float2bfloat16(f);
  return *(unsigned short*)&h;
}

__device__ __forceinline__ float bits2f(unsigned short u) {
  unsigned int x = ((unsigned int)u) << 16;
  return *(float*)&x;
}

__device__ __forceinline__ void gload_lds16(const void* g, void* l) {
  __builtin_amdgcn_global_load_lds(
      (const __attribute__((address_space(1))) void*)g,
      (__attribute__((address_space(3))) void*)l, 16, 0, 0);
}

// ---------------- f32 -> bf16 convert ----------------
__global__ __launch_bounds__(256) void f32_to_bf16_k(const float* __restrict__ in,
    __hip_bfloat16* __restrict__ out) {
  size_t i = ((size_t)blockIdx.x * 256 + threadIdx.x) << 2;
  float4 v = *(const float4*)(in + i);
  ushort4 o;
  o.x = bf16bits(v.x); o.y = bf16bits(v.y); o.z = bf16bits(v.z); o.w = bf16bits(v.w);
  *(ushort4*)((unsigned short*)out + i) = o;
}

// ---------------- transpose W(K,N) f32 -> WT(N,K) bf16 ----------------
__global__ __launch_bounds__(256) void transpose_bf16(const float* __restrict__ W,
    __hip_bfloat16* __restrict__ WT, int K, int N) {
  __shared__ float tile[32][33];
  int t = threadIdx.x;
  int r = t >> 3, c4 = (t & 7) << 2;
  int n0 = blockIdx.x << 5, k0 = blockIdx.y << 5;
  float4 v = *(const float4*)(W + (size_t)(k0 + r) * N + n0 + c4);
  tile[r][c4] = v.x; tile[r][c4 + 1] = v.y; tile[r][c4 + 2] = v.z; tile[r][c4 + 3] = v.w;
  __syncthreads();
  ushort4 o;
  o.x = bf16bits(tile[c4][r]);
  o.y = bf16bits(tile[c4 + 1][r]);
  o.z = bf16bits(tile[c4 + 2][r]);
  o.w = bf16bits(tile[c4 + 3][r]);
  *(ushort4*)((unsigned short*)WT + (size_t)(n0 + r) * K + k0 + c4) = o;
}

// ---------------- bf16 MFMA GEMM (m97 structure) ----------------
__global__ __launch_bounds__(256) void gemm_bf16(
    const __hip_bfloat16* __restrict__ A, const __hip_bfloat16* __restrict__ BT,
    const float* __restrict__ bias, float* __restrict__ C, int M, int N, int K) {
  __shared__ __align__(16) __hip_bfloat16 Asm[4096];
  __shared__ __align__(16) __hip_bfloat16 Bsm[4096];
  int tid = threadIdx.x;
  int lane = tid & 63, wave = tid >> 6;
  int wm = wave >> 1, wn = wave & 1;
  int rowBase = blockIdx.y * 128, colBase = blockIdx.x * 128;
  f32x4 acc[4][4];
  #pragma unroll
  for (int i = 0; i < 4; ++i)
    #pragma unroll
    for (int j = 0; j < 4; ++j) acc[i][j] = (f32x4){0.f, 0.f, 0.f, 0.f};

  for (int kt = 0; kt < K; kt += 32) {
    __syncthreads();
    #pragma unroll
    for (int it = 0; it < 2; ++it) {
      int s = tid + (it << 8);
      int T = s >> 6, q = (s >> 4) & 3, m = s & 15;
      const __hip_bfloat16* ga = A + (size_t)(rowBase + T * 16 + m) * K + kt + q * 8;
      gload_lds16(ga, Asm + s * 8);
      const __hip_bfloat16* gb = BT + (size_t)(colBase + T * 16 + m) * K + kt + q * 8;
      gload_lds16(gb, Bsm + s * 8);
    }
    __syncthreads();
    short8 af[4], bfr[4];
    #pragma unroll
    for (int i = 0; i < 4; ++i) {
      af[i]  = *(const short8*)(Asm + ((wm * 4 + i) << 9) + lane * 8);
      bfr[i] = *(const short8*)(Bsm + ((wn * 4 + i) << 9) + lane * 8);
    }
    #pragma unroll
    for (int i = 0; i < 4; ++i)
      #pragma unroll
      for (int j = 0; j < 4; ++j)
        acc[i][j] = __builtin_amdgcn_mfma_f32_16x16x32_bf16(af[i], bfr[j], acc[i][j], 0, 0, 0);
  }
  int r0 = (lane >> 4) * 4, c0 = lane & 15;
  #pragma unroll
  for (int i = 0; i < 4; ++i) {
    int row = rowBase + (wm * 4 + i) * 16 + r0;
    #pragma unroll
    for (int j = 0; j < 4; ++j) {
      int col = colBase + (wn * 4 + j) * 16 + c0;
      float bs = bias ? bias[col] : 0.f;
      #pragma unroll
      for (int r = 0; r < 4; ++r)
        C[(size_t)(row + r) * N + col] = acc[i][j][r] + bs;
    }
  }
}

// ---------------- depthwise causal conv (K=4) + SiLU ----------------
__global__ __launch_bounds__(256) void conv_silu(const float* __restrict__ in,
    const float* __restrict__ w, float* __restrict__ out) {
  int idx = blockIdx.x * 256 + threadIdx.x;
  int c = idx & (C_ - 1);
  int l = (idx >> 10) & (L_ - 1);
  float acc = 0.f;
  #pragma unroll
  for (int j = 0; j < 4; ++j) {
    int ll = l - 3 + j;
    if (ll >= 0) acc += w[(c << 2) + j] * in[idx + ((j - 3) << 10)];
  }
  out[idx] = acc / (1.f + expf(-acc));
}

// ---------------- beta = sigmoid(x @ Wb) ----------------
__global__ __launch_bounds__(256) void beta_kernel(const float* __restrict__ x,
    const float* __restrict__ Wb, float* __restrict__ beta) {
  int row = blockIdx.x;
  int t = threadIdx.x;
  int h = t >> 6, lane = t & 63;
  const float* xr = x + (size_t)row * D_;
  float acc = 0.f;
  for (int k = lane; k < D_; k += 64) acc += xr[k] * Wb[(k << 2) + h];
  #pragma unroll
  for (int o = 32; o > 0; o >>= 1) acc += __shfl_down(acc, o, 64);
  if (lane == 0) beta[(row << 2) + h] = 1.f / (1.f + expf(-acc));
}

// ---------------- l2norm q,k; v*beta; kb; transpose BLHD -> BHLD ----------------
__global__ __launch_bounds__(256) void precompute(const float* __restrict__ q,
    const float* __restrict__ k, const float* __restrict__ v,
    const float* __restrict__ beta,
    float* __restrict__ qn, float* __restrict__ kn,
    float* __restrict__ vb, float* __restrict__ kb) {
  __shared__ float red[4];
  int bid = blockIdx.x;
  int t = threadIdx.x;
  int b = bid >> 14;
  int h = (bid >> 12) & 3;
  int l = bid & (L_ - 1);
  size_t in_off = (((size_t)(b * L_ + l)) << 10) + (h << 8) + t;
  float qv = q[in_off], kv = k[in_off], vv = v[in_off];
  float sq = block_sum256(qv * qv, red);
  float sk = block_sum256(kv * kv, red);
  float rq = rsqrtf(sq + 1e-6f);
  float rk = rsqrtf(sk + 1e-6f);
  float bt = beta[((b * L_ + l) << 2) + h];
  size_t oo = ((size_t)bid << 8) + t;
  float knv = kv * rk;
  qn[oo] = qv * rq;
  kn[oo] = knv;
  vb[oo] = vv * bt;
  kb[oo] = knv * bt;
}

// ---------------- per-chunk: inv (fwd-subst, bf16-rounded) + attn + knT ----------------
// knT_bf ALIASES kn's region (strided ci<<14 bf16 elems = same 32KB chunk slot);
// kn chunk is fully staged to LDS before the aliasing write. No __restrict__ on pair.
__global__ __launch_bounds__(256) void inv_attn(const float* __restrict__ qn,
    const float* kn, const float* __restrict__ kb,
    float* __restrict__ invb, __hip_bfloat16* __restrict__ att_bf,
    __hip_bfloat16* knT_bf) {
  __shared__ float kn_s[32][257];
  __shared__ float inv_s[32][33];
  int ci = blockIdx.x;
  int t = threadIdx.x;
  size_t base = ((size_t)ci) << 13;
  for (int e = t; e < 8192; e += 256) kn_s[e >> 8][e & 255] = kn[base + e];
  __syncthreads();
  // knT (256 x 32) bf16: thread t writes row d=t into its own chunk slot
  {
    unsigned short tmp[32];
    #pragma unroll
    for (int j = 0; j < 32; ++j) tmp[j] = bf16bits(kn_s[j][t]);
    uint4* dst = (uint4*)((unsigned short*)knT_bf + (((size_t)ci) << 14) + (size_t)t * 32);
    const uint4* src = (const uint4*)tmp;
    #pragma unroll
    for (int i = 0; i < 4; ++i) dst[i] = src[i];
  }
  #pragma unroll
  for (int p = 0; p < 4; ++p) {
    int e = t + (p << 8);
    int i = e >> 5, j = e & 31;
    const float* kbi = kb + base + (i << 8);
    const float* qni = qn + base + (i << 8);
    float am = 0.f, aa = 0.f;
    for (int kk = 0; kk < 256; ++kk) {
      float knv = kn_s[j][kk];
      am += kbi[kk] * knv;
      aa += qni[kk] * knv;
    }
    inv_s[i][j] = (j < i) ? -am : 0.f;
    att_bf[((size_t)ci << 10) + e] = __float2bfloat16((j <= i) ? aa : 0.f);
  }
  __syncthreads();
  for (int i = 1; i < 32; ++i) {
    float upd = 0.f;
    if (t < i) {
      for (int kk = t + 1; kk < i; ++kk) upd += inv_s[i][kk] * inv_s[kk][t];
    }
    __syncthreads();
    if (t < i) inv_s[i][t] += upd;
    __syncthreads();
  }
  #pragma unroll
  for (int p = 0; p < 4; ++p) {
    int e = t + (p << 8);
    int i = e >> 5, j = e & 31;
    float val = inv_s[i][j] + (i == j ? 1.f : 0.f);
    val = __bfloat162float(__float2bfloat16(val));
    invb[((size_t)ci << 10) + e] = val;
  }
}

// ---------------- u = inv@vb (in place f32); w = -(inv@kb) as bf16 in-place ----------------
// w_bf ALIASES kb's region (strided ci<<14); kb chunk fully staged to LDS first.
__global__ __launch_bounds__(256) void uw_kernel(const float* __restrict__ invb,
    float* __restrict__ vb_u, float* kb_w, __hip_bfloat16* w_bf) {
  __shared__ float inv_s[32][33];
  __shared__ float tile[32][260];
  int ci = blockIdx.x, t = threadIdx.x;
  size_t base = ((size_t)ci) << 13;
  for (int e = t; e < 1024; e += 256) inv_s[e >> 5][e & 31] = invb[((size_t)ci << 10) + e];
  for (int ph = 0; ph < 2; ++ph) {
    const float* src = (ph == 0) ? vb_u : kb_w;
    __syncthreads();
    for (int f = t; f < 2048; f += 256) {
      int e = f << 2;
      *(float4*)&tile[e >> 8][e & 255] = *(const float4*)(src + base + e);
    }
    __syncthreads();
    int c4 = (t & 63) << 2;
    int ig = t >> 6;
    float4 acc[8];
    #pragma unroll
    for (int ii = 0; ii < 8; ++ii) acc[ii] = make_float4(0.f, 0.f, 0.f, 0.f);
    for (int j = 0; j < 32; ++j) {
      float4 v4 = *(const float4*)&tile[j][c4];
      #pragma unroll
      for (int ii = 0; ii < 8; ++ii) {
        float iv = inv_s[(ig << 3) + ii][j];
        acc[ii].x += iv * v4.x; acc[ii].y += iv * v4.y;
        acc[ii].z += iv * v4.z; acc[ii].w += iv * v4.w;
      }
    }
    #pragma unroll
    for (int ii = 0; ii < 8; ++ii) {
      int i = (ig << 3) + ii;
      if (ph == 0) {
        *(float4*)(vb_u + base + (i << 8) + c4) = acc[ii];
      } else {
        ushort4 o;  // pre-negated: scan phase A computes u + (-w)@S
        o.x = bf16bits(-acc[ii].x); o.y = bf16bits(-acc[ii].y);
        o.z = bf16bits(-acc[ii].z); o.w = bf16bits(-acc[ii].w);
        *(ushort4*)((unsigned short*)w_bf + (((size_t)ci) << 14) + (i << 8) + c4) = o;
      }
    }
  }
}

// ---------------- MFMA sequential chunk scan ----------------
// grid = 128: bh = blockIdx&7 (same-XCD L2 sharing), cb = blockIdx>>3 (16-col slice).
// S held as hi+lo bf16 pair in LDS (~17-bit mantissa); phases A/B are ds_read+MFMA only.
__global__ __launch_bounds__(256) void scan_kernel(
    const float* __restrict__ qn, const __hip_bfloat16* __restrict__ w_bf,
    const __hip_bfloat16* __restrict__ knT_bf, const __hip_bfloat16* __restrict__ att_bf,
    const float* __restrict__ u, float* __restrict__ dout) {
  __shared__ __align__(16) unsigned short Wb[32 * 264];   // w then qn (bf16), row pad +8
  __shared__ __align__(16) unsigned short KTb[256 * 40];  // knT rows pad to 40
  __shared__ __align__(16) unsigned short ATb[32 * 40];   // attn rows pad to 40
  __shared__ __align__(16) float UtT[16 * 36];            // ut^T [c][r]
  __shared__ __align__(16) unsigned short Shi[16 * 264];  // S^T hi [c][d]
  __shared__ __align__(16) unsigned short Slo[16 * 264];  // S^T lo [c][d]
  int t = threadIdx.x;
  int bh = blockIdx.x & 7;
  int cb = blockIdx.x >> 3;
  int cbase = cb << 4;
  int lane = t & 63, wave = t >> 6;
  int mlane = lane & 15, quad = lane >> 4;
  for (int e = t; e < 16 * 264; e += 256) { Shi[e] = 0; Slo[e] = 0; }

  uint4 wr[4], qr[4], kr[4]; uint2 ar; float ur[4];
  auto load_wka = [&](int nc) {
    int ci = bh * NCH_ + nc;
    size_t cb14 = ((size_t)ci) << 14;
    const uint4* wg = (const uint4*)((const unsigned short*)w_bf + cb14 + (size_t)t * 32);
    const uint4* kg = (const uint4*)((const unsigned short*)knT_bf + cb14 + (size_t)t * 32);
    #pragma unroll
    for (int i = 0; i < 4; ++i) { wr[i] = wg[i]; kr[i] = kg[i]; }
    ar = ((const uint2*)((const unsigned short*)att_bf + (((size_t)ci) << 10)))[t];
  };
  auto load_qu = [&](int nc) {
    int ci = bh * NCH_ + nc;
    size_t cbf = ((size_t)ci) << 13;
    const float4* qgf = (const float4*)(qn + cbf + (size_t)t * 32);
    unsigned short qs16[32];
    #pragma unroll
    for (int i = 0; i < 8; ++i) {
      float4 f = qgf[i];
      qs16[i * 4 + 0] = bf16bits(f.x); qs16[i * 4 + 1] = bf16bits(f.y);
      qs16[i * 4 + 2] = bf16bits(f.z); qs16[i * 4 + 3] = bf16bits(f.w);
    }
    #pragma unroll
    for (int i = 0; i < 4; ++i) qr[i] = ((const uint4*)qs16)[i];
    if (wave < 2) {
      const float* up = u + cbf + (size_t)(wave * 16 + quad * 4) * 256 + cbase + mlane;
      #pragma unroll
      for (int r = 0; r < 4; ++r) ur[r] = up[r * 256];
    }
  };
  auto dump_wka = [&]() {
    int r = t >> 3, k0 = (t & 7) << 5;
    uint4* dw = (uint4*)&Wb[r * 264 + k0];
    #pragma unroll
    for (int i = 0; i < 4; ++i) dw[i] = wr[i];
    uint4* dk = (uint4*)&KTb[t * 40];
    #pragma unroll
    for (int i = 0; i < 4; ++i) dk[i] = kr[i];
    *(uint2*)&ATb[(t >> 3) * 40 + ((t & 7) << 2)] = ar;
  };
  auto dump_qn = [&]() {
    int r = t >> 3, k0 = (t & 7) << 5;
    uint4* dq = (uint4*)&Wb[r * 264 + k0];
    #pragma unroll
    for (int i = 0; i < 4; ++i) dq[i] = qr[i];
  };

  load_wka(0);
  load_qu(0);
  dump_wka();
  __syncthreads();

  for (int nc = 0; nc < NCH_; ++nc) {
    int nn = nc + 1 < NCH_ ? nc + 1 : NCH_ - 1;
    load_wka(nn);
    size_t cbf = ((size_t)(bh * NCH_ + nc)) << 13;
    // ---- phase A: ut = u + (-w) @ S  (waves 0,1) ----
    if (wave < 2) {
      f32x4 acc = (f32x4){ur[0], ur[1], ur[2], ur[3]};
      #pragma unroll
      for (int kt = 0; kt < 8; ++kt) {
        short8 a = *(const short8*)&Wb[(wave * 16 + mlane) * 264 + kt * 32 + quad * 8];
        short8 shi = *(const short8*)&Shi[mlane * 264 + kt * 32 + quad * 8];
        short8 slo = *(const short8*)&Slo[mlane * 264 + kt * 32 + quad * 8];
        acc = __builtin_amdgcn_mfma_f32_16x16x32_bf16(a, shi, acc, 0, 0, 0);
        acc = __builtin_amdgcn_mfma_f32_16x16x32_bf16(a, slo, acc, 0, 0, 0);
      }
      *(float4*)&UtT[mlane * 36 + wave * 16 + quad * 4] =
          make_float4(acc[0], acc[1], acc[2], acc[3]);
    }
    __syncthreads();  // B1: phase A done (Wb reads, UtT writes)
    dump_qn();
    __syncthreads();  // B1b: qn visible in Wb
    load_qu(nn);
    f32x4 accc[8];
    if (wave < 2) {
      // ---- phase B: o = qn @ S + attn @ ut ----
      f32x4 acc = (f32x4){0.f, 0.f, 0.f, 0.f};
      #pragma unroll
      for (int kt = 0; kt < 8; ++kt) {
        short8 a = *(const short8*)&Wb[(wave * 16 + mlane) * 264 + kt * 32 + quad * 8];
        short8 shi = *(const short8*)&Shi[mlane * 264 + kt * 32 + quad * 8];
        short8 slo = *(const short8*)&Slo[mlane * 264 + kt * 32 + quad * 8];
        acc = __builtin_amdgcn_mfma_f32_16x16x32_bf16(a, shi, acc, 0, 0, 0);
        acc = __builtin_amdgcn_mfma_f32_16x16x32_bf16(a, slo, acc, 0, 0, 0);
      }
      short8 aat = *(const short8*)&ATb[(wave * 16 + mlane) * 40 + quad * 8];
      short8 but;
      {
        const float* up = &UtT[mlane * 36 + quad * 8];
        #pragma unroll
        for (int j = 0; j < 8; ++j) but[j] = (short)bf16bits(up[j]);
      }
      acc = __builtin_amdgcn_mfma_f32_16x16x32_bf16(aat, but, acc, 0, 0, 0);
      float* op = dout + cbf + (size_t)(wave * 16 + quad * 4) * 256 + cbase + mlane;
      op[0] = acc[0]; op[256] = acc[1]; op[512] = acc[2]; op[768] = acc[3];
    } else {
      // ---- phase C: S_inc = knT @ ut ----
      int wv = wave - 2;
      short8 but;
      {
        const float* up = &UtT[mlane * 36 + quad * 8];
        #pragma unroll
        for (int j = 0; j < 8; ++j) but[j] = (short)bf16bits(up[j]);
      }
      #pragma unroll
      for (int mt = 0; mt < 8; ++mt) {
        int tile = wv * 8 + mt;
        short8 a = *(const short8*)&KTb[(tile * 16 + mlane) * 40 + quad * 8];
        f32x4 z = (f32x4){0.f, 0.f, 0.f, 0.f};
        accc[mt] = __builtin_amdgcn_mfma_f32_16x16x32_bf16(a, but, z, 0, 0, 0);
      }
    }
    __syncthreads();  // B3: phase B/C done (St reads, UtT reads)
    if (wave >= 2) {
      int wv = wave - 2;
      #pragma unroll
      for (int mt = 0; mt < 8; ++mt) {
        int d0 = (wv * 8 + mt) * 16 + quad * 4;
        unsigned short* hp = &Shi[mlane * 264 + d0];
        unsigned short* lp = &Slo[mlane * 264 + d0];
        uint2 hb = *(uint2*)hp;
        uint2 lb = *(uint2*)lp;
        unsigned short* h4 = (unsigned short*)&hb;
        unsigned short* l4 = (unsigned short*)&lb;
        unsigned short nh[4], nl[4];
        #pragma unroll
        for (int r = 0; r < 4; ++r) {
          float s = bits2f(h4[r]) + bits2f(l4[r]) + accc[mt][r];
          unsigned short hbit = bf16bits(s);
          nh[r] = hbit;
          nl[r] = bf16bits(s - bits2f(hbit));
        }
        *(uint2*)hp = *(uint2*)nh;
        *(uint2*)lp = *(uint2*)nl;
      }
    }
    dump_wka();
    __syncthreads();  // B2: S updated + next chunk staged
  }
}

// ---------------- FIR convs + gate MLP + softmax(floor) + fuse + RMSNorm ----------------
__global__ __launch_bounds__(256) void gate_kernel(const float* __restrict__ v,
    const float* __restrict__ delta, const float* __restrict__ qg,
    const float* __restrict__ fw0, const float* __restrict__ fw1,
    const float* __restrict__ fw2, const float* __restrict__ fw3,
    const float* __restrict__ Wf1, const float* __restrict__ bf1,
    const float* __restrict__ Wf2, const float* __restrict__ bf2,
    const float* __restrict__ ltm, const float* __restrict__ onw,
    float* __restrict__ o, __hip_bfloat16* __restrict__ obf) {
  __shared__ float red[4];
  __shared__ float gin[GIN_c];
  __shared__ float hm[GH_c];
  __shared__ float lg[NS_c];
  __shared__ float pj[NS_c];
  int bl = blockIdx.x, t = threadIdx.x;
  int b = bl >> 12, l = bl & (L_ - 1);
  if (t < GQP_c) gin[t] = qg[((size_t)bl << 7) + t];
  __syncthreads();
  for (int h = 0; h < H_; ++h) {
    int c = (h << 8) + t;
    float st[6];
    size_t vcur = (((size_t)bl) << 10) + c;
    float v0 = v[vcur];
    st[0] = fw0[c] * v0;
    st[5] = v0;
    float a1 = 0.f;
    #pragma unroll
    for (int j = 0; j < 3; ++j) {
      int ll = l - 2 + j;
      if (ll >= 0) a1 += fw1[c * 3 + j] * v[(((size_t)(b * L_ + ll)) << 10) + c];
    }
    st[1] = a1;
    float a2 = 0.f;
    #pragma unroll
    for (int j = 0; j < 7; ++j) {
      int ll = l - 6 + j;
      if (ll >= 0) a2 += fw2[c * 7 + j] * v[(((size_t)(b * L_ + ll)) << 10) + c];
    }
    st[2] = a2;
    float a3 = 0.f;
    #pragma unroll
    for (int j = 0; j < 15; ++j) {
      int ll = l - 14 + j;
      if (ll >= 0) a3 += fw3[c * 15 + j] * v[(((size_t)(b * L_ + ll)) << 10) + c];
    }
    st[3] = a3;
    st[4] = delta[(((size_t)((b * H_ + h) * L_ + l)) << 8) + t];
    #pragma unroll
    for (int j = 0; j < 6; ++j) {
      float s = block_sum256(st[j], red);
      if (t == 0) gin[GQP_c + j] = s * (1.f / 256.f);
    }
    __syncthreads();
    if (t < GH_c) {
      float a = bf1[t];
      for (int i = 0; i < GIN_c; ++i) a += gin[i] * Wf1[i * GH_c + t];
      hm[t] = 0.5f * a * (1.f + erff(a * 0.70710678f));
    }
    __syncthreads();
    if (t < NS_c) {
      float a = bf2[t];
      for (int i = 0; i < GH_c; ++i) a += hm[i] * Wf2[i * NS_c + t];
      lg[t] = a / expf(ltm[h]);
    }
    __syncthreads();
    if (t == 0) {
      float m = lg[0];
      for (int j = 1; j < 6; ++j) m = fmaxf(m, lg[j]);
      float ssum = 0.f;
      float e[6];
      for (int j = 0; j < 6; ++j) { e[j] = expf(lg[j] - m); ssum += e[j]; }
      for (int j = 0; j < 6; ++j) pj[j] = e[j] / ssum * 0.88f + 0.02f;
    }
    __syncthreads();
    float fused = 0.f;
    #pragma unroll
    for (int j = 0; j < 6; ++j) fused += pj[j] * st[j];
    float ssq = block_sum256(fused * fused, red);
    float sc = rsqrtf(ssq * (1.f / 256.f) + 1e-5f);
    float ov = fused * sc * onw[t];
    o[vcur] = ov;
    obf[vcur] = __float2bfloat16(ov);
    __syncthreads();
  }
}

// ---------------- launch ----------------
extern "C" void kernel_launch(void* const* d_in, const int* in_sizes, int n_in,
                              void* d_out, int out_size, void* d_ws, size_t ws_size,
                              hipStream_t stream) {
  const float* x   = (const float*)d_in[0];
  const float* Wq  = (const float*)d_in[1];
  const float* Wk  = (const float*)d_in[2];
  const float* Wv  = (const float*)d_in[3];
  const float* Wb  = (const float*)d_in[4];
  const float* cqw = (const float*)d_in[5];
  const float* ckw = (const float*)d_in[6];
  const float* cvw = (const float*)d_in[7];
  const float* fw0 = (const float*)d_in[8];
  const float* fw1 = (const float*)d_in[9];
  const float* fw2 = (const float*)d_in[10];
  const float* fw3 = (const float*)d_in[11];
  const float* Wqg = (const float*)d_in[12];
  const float* bqg = (const float*)d_in[13];
  const float* Wf1 = (const float*)d_in[14];
  const float* bf1 = (const float*)d_in[15];
  const float* Wf2 = (const float*)d_in[16];
  const float* bf2 = (const float*)d_in[17];
  const float* ltm = (const float*)d_in[18];
  const float* onw = (const float*)d_in[19];
  const float* Wo  = (const float*)d_in[20];
  float* out = (float*)d_out;
  float* ws = (float*)d_ws;

  // ws footprint identical to the passing round-2 layout (~247.6 MB).
  const size_t BIG = (size_t)BL_ * C_;
  float* qpre = ws;                 // -> qn f32 (scan reads) -> gate_bf after scan
  float* kpre = ws + BIG;           // -> kn f32 -> knT_bf (bf16, strided in-place)
  float* vpre = ws + 2 * BIG;       // -> vb -> u f32 (scan reads)
  float* qs   = ws + 3 * BIG;       // x_bf early -> conv q -> delta_out (scan writes)
  float* ks   = ws + 4 * BIG;       // conv k -> gate output
  float* vs   = ws + 5 * BIG;       // conv v (FIR/v_direct)
  float* kbw  = ws + 6 * BIG;       // wT bf16 early -> kb -> w_bf (strided) -> woT
  float* invb = ws + 7 * BIG;
  float* attb = invb + (size_t)1024 * 1024;   // att_bf (2MB) inside this 4MB region
  float* beta = attb + (size_t)1024 * 1024;
  float* qg   = beta + (size_t)BL_ * H_;

  __hip_bfloat16* x_bf  = (__hip_bfloat16*)qs;
  __hip_bfloat16* wqT   = (__hip_bfloat16*)kbw;
  __hip_bfloat16* wkT   = wqT + (size_t)1024 * 1024;
  __hip_bfloat16* wvT   = wkT + (size_t)1024 * 1024;
  __hip_bfloat16* wqgT  = wvT + (size_t)1024 * 1024;
  __hip_bfloat16* woT   = (__hip_bfloat16*)kbw;   // written after scan consumed w_bf
  __hip_bfloat16* gate_bf = (__hip_bfloat16*)qpre; // written after scan consumed qn
  __hip_bfloat16* knT_bf = (__hip_bfloat16*)kpre;  // strided per-chunk, by inv_attn
  __hip_bfloat16* w_bf   = (__hip_bfloat16*)kbw;   // strided per-chunk, by uw_kernel
  __hip_bfloat16* att_bf = (__hip_bfloat16*)attb;

  dim3 blk(256);
  f32_to_bf16_k<<<dim3(BL_ * D_ / 1024), blk, 0, stream>>>(x, x_bf);
  transpose_bf16<<<dim3(32, 32), blk, 0, stream>>>(Wq, wqT, D_, C_);
  transpose_bf16<<<dim3(32, 32), blk, 0, stream>>>(Wk, wkT, D_, C_);
  transpose_bf16<<<dim3(32, 32), blk, 0, stream>>>(Wv, wvT, D_, C_);
  transpose_bf16<<<dim3(4, 32), blk, 0, stream>>>(Wqg, wqgT, D_, GQP_c);
  gemm_bf16<<<dim3(8, 64), blk, 0, stream>>>(x_bf, wqT, nullptr, qpre, BL_, C_, D_);
  gemm_bf16<<<dim3(8, 64), blk, 0, stream>>>(x_bf, wkT, nullptr, kpre, BL_, C_, D_);
  gemm_bf16<<<dim3(8, 64), blk, 0, stream>>>(x_bf, wvT, nullptr, vpre, BL_, C_, D_);
  gemm_bf16<<<dim3(1, 64), blk, 0, stream>>>(x_bf, wqgT, bqg, qg, BL_, GQP_c, D_);
  beta_kernel<<<dim3(BL_), blk, 0, stream>>>(x, Wb, beta);
  conv_silu<<<dim3(BL_ * C_ / 256), blk, 0, stream>>>(qpre, cqw, qs);
  conv_silu<<<dim3(BL_ * C_ / 256), blk, 0, stream>>>(kpre, ckw, ks);
  conv_silu<<<dim3(BL_ * C_ / 256), blk, 0, stream>>>(vpre, cvw, vs);
  precompute<<<dim3(B_ * H_ * L_), blk, 0, stream>>>(qs, ks, vs, beta, qpre, kpre,
                                                     vpre, kbw);
  inv_attn<<<dim3(1024), blk, 0, stream>>>(qpre, kpre, kbw, invb, att_bf, knT_bf);
  uw_kernel<<<dim3(1024), blk, 0, stream>>>(invb, vpre, kbw, w_bf);
  scan_kernel<<<dim3(128), blk, 0, stream>>>(qpre, w_bf, knT_bf, att_bf, vpre, qs);
  transpose_bf16<<<dim3(32, 32), blk, 0, stream>>>(Wo, woT, C_, D_);
  gate_kernel<<<dim3(BL_), blk, 0, stream>>>(vs, qs, qg, fw0, fw1, fw2, fw3,
                                             Wf1, bf1, Wf2, bf2, ltm, onw, ks, gate_bf);
  gemm_bf16<<<dim3(8, 64), blk, 0, stream>>>(gate_bf, woT, nullptr, out, BL_, D_, C_);
}

// Round 6
// 1486.601 us; speedup vs baseline: 2.3154x; 1.1334x over previous
//
#include <hip/hip_runtime.h>
#include <hip/hip_bf16.h>
#include <math.h>

#define B_ 2
#define L_ 4096
#define D_ 1024
#define H_ 4
#define DK_ 256
#define BL_ 8192
#define C_ 1024
#define NCH_ 128
#define GQP_c 128
#define NS_c 6
#define GIN_c 134
#define GH_c 134

typedef __attribute__((ext_vector_type(8))) short short8;
typedef __attribute__((ext_vector_type(4))) float f32x4;

// ---------------- helpers ----------------
__device__ __forceinline__ float block_sum256(float v, float* red) {
  int t = threadIdx.x;
  #pragma unroll
  for (int o = 32; o > 0; o >>= 1) v += __shfl_down(v, o, 64);
  __syncthreads();
  if ((t & 63) == 0) red[t >> 6] = v;
  __syncthreads();
  return red[0] + red[1] + red[2] + red[3];
}

__device__ __forceinline__ unsigned short bf16bits(float f) {
  __hip_bfloat16 h = __float2bfloat16(f);
  return *(unsigned short*)&h;
}

__device__ __forceinline__ float bits2f(unsigned short u) {
  unsigned int x = ((unsigned int)u) << 16;
  return *(float*)&x;
}

__device__ __forceinline__ float4 fma4(float4 a, float4 b, float4 c) {
  return make_float4(fmaf(a.x, b.x, c.x), fmaf(a.y, b.y, c.y),
                     fmaf(a.z, b.z, c.z), fmaf(a.w, b.w, c.w));
}

__device__ __forceinline__ void gload_lds16(const void* g, void* l) {
  __builtin_amdgcn_global_load_lds(
      (const __attribute__((address_space(1))) void*)g,
      (__attribute__((address_space(3))) void*)l, 16, 0, 0);
}

// ---------------- f32 -> bf16 convert ----------------
__global__ __launch_bounds__(256) void f32_to_bf16_k(const float* __restrict__ in,
    __hip_bfloat16* __restrict__ out) {
  size_t i = ((size_t)blockIdx.x * 256 + threadIdx.x) << 2;
  float4 v = *(const float4*)(in + i);
  ushort4 o;
  o.x = bf16bits(v.x); o.y = bf16bits(v.y); o.z = bf16bits(v.z); o.w = bf16bits(v.w);
  *(ushort4*)((unsigned short*)out + i) = o;
}

// ---------------- transpose W(K,N) f32 -> WT(N,K) bf16 ----------------
__global__ __launch_bounds__(256) void transpose_bf16(const float* __restrict__ W,
    __hip_bfloat16* __restrict__ WT, int K, int N) {
  __shared__ float tile[32][33];
  int t = threadIdx.x;
  int r = t >> 3, c4 = (t & 7) << 2;
  int n0 = blockIdx.x << 5, k0 = blockIdx.y << 5;
  float4 v = *(const float4*)(W + (size_t)(k0 + r) * N + n0 + c4);
  tile[r][c4] = v.x; tile[r][c4 + 1] = v.y; tile[r][c4 + 2] = v.z; tile[r][c4 + 3] = v.w;
  __syncthreads();
  ushort4 o;
  o.x = bf16bits(tile[c4][r]);
  o.y = bf16bits(tile[c4 + 1][r]);
  o.z = bf16bits(tile[c4 + 2][r]);
  o.w = bf16bits(tile[c4 + 3][r]);
  *(ushort4*)((unsigned short*)WT + (size_t)(n0 + r) * K + k0 + c4) = o;
}

// ---------------- small f32 transpose with zero-pad: out[c*OS+r] = in[r*Cc+c] ----------------
__global__ __launch_bounds__(256) void small_transpose(const float* __restrict__ in,
    float* __restrict__ out, int R, int Cc, int OS) {
  int total = Cc * OS;
  for (int e = blockIdx.x * 256 + threadIdx.x; e < total; e += gridDim.x * 256) {
    int cIdx = e / OS, r = e - cIdx * OS;
    out[e] = (r < R) ? in[(size_t)r * Cc + cIdx] : 0.f;
  }
}

// ---------------- bf16 MFMA GEMM (m97 structure) ----------------
__global__ __launch_bounds__(256) void gemm_bf16(
    const __hip_bfloat16* __restrict__ A, const __hip_bfloat16* __restrict__ BT,
    const float* __restrict__ bias, float* __restrict__ C, int M, int N, int K) {
  __shared__ __align__(16) __hip_bfloat16 Asm[4096];
  __shared__ __align__(16) __hip_bfloat16 Bsm[4096];
  int tid = threadIdx.x;
  int lane = tid & 63, wave = tid >> 6;
  int wm = wave >> 1, wn = wave & 1;
  int rowBase = blockIdx.y * 128, colBase = blockIdx.x * 128;
  f32x4 acc[4][4];
  #pragma unroll
  for (int i = 0; i < 4; ++i)
    #pragma unroll
    for (int j = 0; j < 4; ++j) acc[i][j] = (f32x4){0.f, 0.f, 0.f, 0.f};

  for (int kt = 0; kt < K; kt += 32) {
    __syncthreads();
    #pragma unroll
    for (int it = 0; it < 2; ++it) {
      int s = tid + (it << 8);
      int T = s >> 6, q = (s >> 4) & 3, m = s & 15;
      const __hip_bfloat16* ga = A + (size_t)(rowBase + T * 16 + m) * K + kt + q * 8;
      gload_lds16(ga, Asm + s * 8);
      const __hip_bfloat16* gb = BT + (size_t)(colBase + T * 16 + m) * K + kt + q * 8;
      gload_lds16(gb, Bsm + s * 8);
    }
    __syncthreads();
    short8 af[4], bfr[4];
    #pragma unroll
    for (int i = 0; i < 4; ++i) {
      af[i]  = *(const short8*)(Asm + ((wm * 4 + i) << 9) + lane * 8);
      bfr[i] = *(const short8*)(Bsm + ((wn * 4 + i) << 9) + lane * 8);
    }
    #pragma unroll
    for (int i = 0; i < 4; ++i)
      #pragma unroll
      for (int j = 0; j < 4; ++j)
        acc[i][j] = __builtin_amdgcn_mfma_f32_16x16x32_bf16(af[i], bfr[j], acc[i][j], 0, 0, 0);
  }
  int r0 = (lane >> 4) * 4, c0 = lane & 15;
  #pragma unroll
  for (int i = 0; i < 4; ++i) {
    int row = rowBase + (wm * 4 + i) * 16 + r0;
    #pragma unroll
    for (int j = 0; j < 4; ++j) {
      int col = colBase + (wn * 4 + j) * 16 + c0;
      float bs = bias ? bias[col] : 0.f;
      #pragma unroll
      for (int r = 0; r < 4; ++r)
        C[(size_t)(row + r) * N + col] = acc[i][j][r] + bs;
    }
  }
}

// ---------------- depthwise causal conv (K=4) + SiLU ----------------
__global__ __launch_bounds__(256) void conv_silu(const float* __restrict__ in,
    const float* __restrict__ w, float* __restrict__ out) {
  int idx = blockIdx.x * 256 + threadIdx.x;
  int c = idx & (C_ - 1);
  int l = (idx >> 10) & (L_ - 1);
  float acc = 0.f;
  #pragma unroll
  for (int j = 0; j < 4; ++j) {
    int ll = l - 3 + j;
    if (ll >= 0) acc += w[(c << 2) + j] * in[idx + ((j - 3) << 10)];
  }
  out[idx] = acc / (1.f + expf(-acc));
}

// ---------------- beta = sigmoid(x @ Wb) ----------------
__global__ __launch_bounds__(256) void beta_kernel(const float* __restrict__ x,
    const float* __restrict__ Wb, float* __restrict__ beta) {
  int row = blockIdx.x;
  int t = threadIdx.x;
  int h = t >> 6, lane = t & 63;
  const float* xr = x + (size_t)row * D_;
  float acc = 0.f;
  for (int k = lane; k < D_; k += 64) acc += xr[k] * Wb[(k << 2) + h];
  #pragma unroll
  for (int o = 32; o > 0; o >>= 1) acc += __shfl_down(acc, o, 64);
  if (lane == 0) beta[(row << 2) + h] = 1.f / (1.f + expf(-acc));
}

// ---------------- l2norm q,k; v*beta; kb; transpose BLHD -> BHLD ----------------
__global__ __launch_bounds__(256) void precompute(const float* __restrict__ q,
    const float* __restrict__ k, const float* __restrict__ v,
    const float* __restrict__ beta,
    float* __restrict__ qn, float* __restrict__ kn,
    float* __restrict__ vb, float* __restrict__ kb) {
  __shared__ float red[4];
  int bid = blockIdx.x;
  int t = threadIdx.x;
  int b = bid >> 14;
  int h = (bid >> 12) & 3;
  int l = bid & (L_ - 1);
  size_t in_off = (((size_t)(b * L_ + l)) << 10) + (h << 8) + t;
  float qv = q[in_off], kv = k[in_off], vv = v[in_off];
  float sq = block_sum256(qv * qv, red);
  float sk = block_sum256(kv * kv, red);
  float rq = rsqrtf(sq + 1e-6f);
  float rk = rsqrtf(sk + 1e-6f);
  float bt = beta[((b * L_ + l) << 2) + h];
  size_t oo = ((size_t)bid << 8) + t;
  float knv = kv * rk;
  qn[oo] = qv * rq;
  kn[oo] = knv;
  vb[oo] = vv * bt;
  kb[oo] = knv * bt;
}

// ---------------- per-chunk: inv (fwd-subst, bf16-rounded) + attn + knT ----------------
__global__ __launch_bounds__(256) void inv_attn(const float* __restrict__ qn,
    const float* kn, const float* __restrict__ kb,
    float* __restrict__ invb, __hip_bfloat16* __restrict__ att_bf,
    __hip_bfloat16* knT_bf) {
  __shared__ float kn_s[32][257];
  __shared__ float inv_s[32][33];
  int ci = blockIdx.x;
  int t = threadIdx.x;
  size_t base = ((size_t)ci) << 13;
  for (int e = t; e < 8192; e += 256) kn_s[e >> 8][e & 255] = kn[base + e];
  __syncthreads();
  {
    unsigned short tmp[32];
    #pragma unroll
    for (int j = 0; j < 32; ++j) tmp[j] = bf16bits(kn_s[j][t]);
    uint4* dst = (uint4*)((unsigned short*)knT_bf + (((size_t)ci) << 14) + (size_t)t * 32);
    const uint4* src = (const uint4*)tmp;
    #pragma unroll
    for (int i = 0; i < 4; ++i) dst[i] = src[i];
  }
  #pragma unroll
  for (int p = 0; p < 4; ++p) {
    int e = t + (p << 8);
    int i = e >> 5, j = e & 31;
    const float* kbi = kb + base + (i << 8);
    const float* qni = qn + base + (i << 8);
    float am = 0.f, aa = 0.f;
    for (int kk = 0; kk < 256; ++kk) {
      float knv = kn_s[j][kk];
      am += kbi[kk] * knv;
      aa += qni[kk] * knv;
    }
    inv_s[i][j] = (j < i) ? -am : 0.f;
    att_bf[((size_t)ci << 10) + e] = __float2bfloat16((j <= i) ? aa : 0.f);
  }
  __syncthreads();
  for (int i = 1; i < 32; ++i) {
    float upd = 0.f;
    if (t < i) {
      for (int kk = t + 1; kk < i; ++kk) upd += inv_s[i][kk] * inv_s[kk][t];
    }
    __syncthreads();
    if (t < i) inv_s[i][t] += upd;
    __syncthreads();
  }
  #pragma unroll
  for (int p = 0; p < 4; ++p) {
    int e = t + (p << 8);
    int i = e >> 5, j = e & 31;
    float val = inv_s[i][j] + (i == j ? 1.f : 0.f);
    val = __bfloat162float(__float2bfloat16(val));
    invb[((size_t)ci << 10) + e] = val;
  }
}

// ---------------- u = inv@vb (in place f32); w = -(inv@kb) as bf16 in-place ----------------
__global__ __launch_bounds__(256) void uw_kernel(const float* __restrict__ invb,
    float* __restrict__ vb_u, float* kb_w, __hip_bfloat16* w_bf) {
  __shared__ float inv_s[32][33];
  __shared__ float tile[32][260];
  int ci = blockIdx.x, t = threadIdx.x;
  size_t base = ((size_t)ci) << 13;
  for (int e = t; e < 1024; e += 256) inv_s[e >> 5][e & 31] = invb[((size_t)ci << 10) + e];
  for (int ph = 0; ph < 2; ++ph) {
    const float* src = (ph == 0) ? vb_u : kb_w;
    __syncthreads();
    for (int f = t; f < 2048; f += 256) {
      int e = f << 2;
      *(float4*)&tile[e >> 8][e & 255] = *(const float4*)(src + base + e);
    }
    __syncthreads();
    int c4 = (t & 63) << 2;
    int ig = t >> 6;
    float4 acc[8];
    #pragma unroll
    for (int ii = 0; ii < 8; ++ii) acc[ii] = make_float4(0.f, 0.f, 0.f, 0.f);
    for (int j = 0; j < 32; ++j) {
      float4 v4 = *(const float4*)&tile[j][c4];
      #pragma unroll
      for (int ii = 0; ii < 8; ++ii) {
        float iv = inv_s[(ig << 3) + ii][j];
        acc[ii].x += iv * v4.x; acc[ii].y += iv * v4.y;
        acc[ii].z += iv * v4.z; acc[ii].w += iv * v4.w;
      }
    }
    #pragma unroll
    for (int ii = 0; ii < 8; ++ii) {
      int i = (ig << 3) + ii;
      if (ph == 0) {
        *(float4*)(vb_u + base + (i << 8) + c4) = acc[ii];
      } else {
        ushort4 o;
        o.x = bf16bits(-acc[ii].x); o.y = bf16bits(-acc[ii].y);
        o.z = bf16bits(-acc[ii].z); o.w = bf16bits(-acc[ii].w);
        *(ushort4*)((unsigned short*)w_bf + (((size_t)ci) << 14) + (i << 8) + c4) = o;
      }
    }
  }
}

// ---------------- MFMA sequential chunk scan ----------------
__global__ __launch_bounds__(256) void scan_kernel(
    const float* __restrict__ qn, const __hip_bfloat16* __restrict__ w_bf,
    const __hip_bfloat16* __restrict__ knT_bf, const __hip_bfloat16* __restrict__ att_bf,
    const float* __restrict__ u, float* __restrict__ dout) {
  __shared__ __align__(16) unsigned short Wb[32 * 264];
  __shared__ __align__(16) unsigned short KTb[256 * 40];
  __shared__ __align__(16) unsigned short ATb[32 * 40];
  __shared__ __align__(16) float UtT[16 * 36];
  __shared__ __align__(16) unsigned short Shi[16 * 264];
  __shared__ __align__(16) unsigned short Slo[16 * 264];
  int t = threadIdx.x;
  int bh = blockIdx.x & 7;
  int cb = blockIdx.x >> 3;
  int cbase = cb << 4;
  int lane = t & 63, wave = t >> 6;
  int mlane = lane & 15, quad = lane >> 4;
  for (int e = t; e < 16 * 264; e += 256) { Shi[e] = 0; Slo[e] = 0; }

  uint4 wr[4], qr[4], kr[4]; uint2 ar; float ur[4];
  auto load_wka = [&](int nc) {
    int ci = bh * NCH_ + nc;
    size_t cb14 = ((size_t)ci) << 14;
    const uint4* wg = (const uint4*)((const unsigned short*)w_bf + cb14 + (size_t)t * 32);
    const uint4* kg = (const uint4*)((const unsigned short*)knT_bf + cb14 + (size_t)t * 32);
    #pragma unroll
    for (int i = 0; i < 4; ++i) { wr[i] = wg[i]; kr[i] = kg[i]; }
    ar = ((const uint2*)((const unsigned short*)att_bf + (((size_t)ci) << 10)))[t];
  };
  auto load_qu = [&](int nc) {
    int ci = bh * NCH_ + nc;
    size_t cbf = ((size_t)ci) << 13;
    const float4* qgf = (const float4*)(qn + cbf + (size_t)t * 32);
    unsigned short qs16[32];
    #pragma unroll
    for (int i = 0; i < 8; ++i) {
      float4 f = qgf[i];
      qs16[i * 4 + 0] = bf16bits(f.x); qs16[i * 4 + 1] = bf16bits(f.y);
      qs16[i * 4 + 2] = bf16bits(f.z); qs16[i * 4 + 3] = bf16bits(f.w);
    }
    #pragma unroll
    for (int i = 0; i < 4; ++i) qr[i] = ((const uint4*)qs16)[i];
    if (wave < 2) {
      const float* up = u + cbf + (size_t)(wave * 16 + quad * 4) * 256 + cbase + mlane;
      #pragma unroll
      for (int r = 0; r < 4; ++r) ur[r] = up[r * 256];
    }
  };
  auto dump_wka = [&]() {
    int r = t >> 3, k0 = (t & 7) << 5;
    uint4* dw = (uint4*)&Wb[r * 264 + k0];
    #pragma unroll
    for (int i = 0; i < 4; ++i) dw[i] = wr[i];
    uint4* dk = (uint4*)&KTb[t * 40];
    #pragma unroll
    for (int i = 0; i < 4; ++i) dk[i] = kr[i];
    *(uint2*)&ATb[(t >> 3) * 40 + ((t & 7) << 2)] = ar;
  };
  auto dump_qn = [&]() {
    int r = t >> 3, k0 = (t & 7) << 5;
    uint4* dq = (uint4*)&Wb[r * 264 + k0];
    #pragma unroll
    for (int i = 0; i < 4; ++i) dq[i] = qr[i];
  };

  load_wka(0);
  load_qu(0);
  dump_wka();
  __syncthreads();

  for (int nc = 0; nc < NCH_; ++nc) {
    int nn = nc + 1 < NCH_ ? nc + 1 : NCH_ - 1;
    load_wka(nn);
    size_t cbf = ((size_t)(bh * NCH_ + nc)) << 13;
    if (wave < 2) {
      f32x4 acc = (f32x4){ur[0], ur[1], ur[2], ur[3]};
      #pragma unroll
      for (int kt = 0; kt < 8; ++kt) {
        short8 a = *(const short8*)&Wb[(wave * 16 + mlane) * 264 + kt * 32 + quad * 8];
        short8 shi = *(const short8*)&Shi[mlane * 264 + kt * 32 + quad * 8];
        short8 slo = *(const short8*)&Slo[mlane * 264 + kt * 32 + quad * 8];
        acc = __builtin_amdgcn_mfma_f32_16x16x32_bf16(a, shi, acc, 0, 0, 0);
        acc = __builtin_amdgcn_mfma_f32_16x16x32_bf16(a, slo, acc, 0, 0, 0);
      }
      *(float4*)&UtT[mlane * 36 + wave * 16 + quad * 4] =
          make_float4(acc[0], acc[1], acc[2], acc[3]);
    }
    __syncthreads();
    dump_qn();
    __syncthreads();
    load_qu(nn);
    f32x4 accc[8];
    if (wave < 2) {
      f32x4 acc = (f32x4){0.f, 0.f, 0.f, 0.f};
      #pragma unroll
      for (int kt = 0; kt < 8; ++kt) {
        short8 a = *(const short8*)&Wb[(wave * 16 + mlane) * 264 + kt * 32 + quad * 8];
        short8 shi = *(const short8*)&Shi[mlane * 264 + kt * 32 + quad * 8];
        short8 slo = *(const short8*)&Slo[mlane * 264 + kt * 32 + quad * 8];
        acc = __builtin_amdgcn_mfma_f32_16x16x32_bf16(a, shi, acc, 0, 0, 0);
        acc = __builtin_amdgcn_mfma_f32_16x16x32_bf16(a, slo, acc, 0, 0, 0);
      }
      short8 aat = *(const short8*)&ATb[(wave * 16 + mlane) * 40 + quad * 8];
      short8 but;
      {
        const float* up = &UtT[mlane * 36 + quad * 8];
        #pragma unroll
        for (int j = 0; j < 8; ++j) but[j] = (short)bf16bits(up[j]);
      }
      acc = __builtin_amdgcn_mfma_f32_16x16x32_bf16(aat, but, acc, 0, 0, 0);
      float* op = dout + cbf + (size_t)(wave * 16 + quad * 4) * 256 + cbase + mlane;
      op[0] = acc[0]; op[256] = acc[1]; op[512] = acc[2]; op[768] = acc[3];
    } else {
      int wv = wave - 2;
      short8 but;
      {
        const float* up = &UtT[mlane * 36 + quad * 8];
        #pragma unroll
        for (int j = 0; j < 8; ++j) but[j] = (short)bf16bits(up[j]);
      }
      #pragma unroll
      for (int mt = 0; mt < 8; ++mt) {
        int tile = wv * 8 + mt;
        short8 a = *(const short8*)&KTb[(tile * 16 + mlane) * 40 + quad * 8];
        f32x4 z = (f32x4){0.f, 0.f, 0.f, 0.f};
        accc[mt] = __builtin_amdgcn_mfma_f32_16x16x32_bf16(a, but, z, 0, 0, 0);
      }
    }
    __syncthreads();
    if (wave >= 2) {
      int wv = wave - 2;
      #pragma unroll
      for (int mt = 0; mt < 8; ++mt) {
        int d0 = (wv * 8 + mt) * 16 + quad * 4;
        unsigned short* hp = &Shi[mlane * 264 + d0];
        unsigned short* lp = &Slo[mlane * 264 + d0];
        uint2 hb = *(uint2*)hp;
        uint2 lb = *(uint2*)lp;
        unsigned short* h4 = (unsigned short*)&hb;
        unsigned short* l4 = (unsigned short*)&lb;
        unsigned short nh[4], nl[4];
        #pragma unroll
        for (int r = 0; r < 4; ++r) {
          float s = bits2f(h4[r]) + bits2f(l4[r]) + accc[mt][r];
          unsigned short hbit = bf16bits(s);
          nh[r] = hbit;
          nl[r] = bf16bits(s - bits2f(hbit));
        }
        *(uint2*)hp = *(uint2*)nh;
        *(uint2*)lp = *(uint2*)nl;
      }
    }
    dump_wka();
    __syncthreads();
  }
}

// ---------------- gate: wave-per-(b,l,h); 4 barriers at LDS comm points ----------------
// LDS per wave: [0..135]=gin, [136..271]=hm(+pad), [272..277]=lg, [280..285]=pj
__global__ __launch_bounds__(256) void gate_kernel(
    const float* __restrict__ v, const float* __restrict__ delta,
    const float* __restrict__ qg,
    const float* __restrict__ fw0, const float* __restrict__ fw1T,
    const float* __restrict__ fw2T, const float* __restrict__ fw3T,
    const float* __restrict__ Wf1T, const float* __restrict__ Wf2T,
    const float* __restrict__ bf1, const float* __restrict__ bf2,
    const float* __restrict__ ltm, const float* __restrict__ onw,
    __hip_bfloat16* __restrict__ obf) {
  __shared__ __align__(16) float sh[4][296];
  int t = threadIdx.x;
  int wave = t >> 6, lane = t & 63;
  int bl = blockIdx.x;
  int b = bl >> 12, l = bl & (L_ - 1);
  int h = wave;
  float* W = sh[wave];
  int c = (h << 8) + (lane << 2);
  size_t vrow = (((size_t)bl) << 10) + c;

  // stage qg row + pad into per-wave gin
  if (lane < 32)
    *(float4*)&W[lane << 2] = *(const float4*)(qg + (((size_t)bl) << 7) + (lane << 2));
  if (lane == 32) { W[134] = 0.f; W[135] = 0.f; }

  // ---- FIR streams (tap-major transposed weights) ----
  float4 st0, st1, st2, st3, st4, st5;
  st1 = make_float4(0, 0, 0, 0);
  st2 = make_float4(0, 0, 0, 0);
  st3 = make_float4(0, 0, 0, 0);
  #pragma unroll
  for (int j = 0; j < 15; ++j) {
    int ll = l - 14 + j;
    float4 vj = make_float4(0, 0, 0, 0);
    if (ll >= 0) vj = *(const float4*)(v + ((((size_t)(b * L_ + ll)) << 10) + c));
    float4 w3 = *(const float4*)(fw3T + (j << 10) + c);
    st3 = fma4(w3, vj, st3);
    if (j >= 8) {
      float4 w2 = *(const float4*)(fw2T + ((j - 8) << 10) + c);
      st2 = fma4(w2, vj, st2);
    }
    if (j >= 12) {
      float4 w1 = *(const float4*)(fw1T + ((j - 12) << 10) + c);
      st1 = fma4(w1, vj, st1);
    }
    if (j == 14) {
      float4 w0 = *(const float4*)(fw0 + c);
      st0 = make_float4(w0.x * vj.x, w0.y * vj.y, w0.z * vj.z, w0.w * vj.w);
      st5 = vj;
    }
  }
  st4 = *(const float4*)(delta + ((((size_t)((b * H_ + h) * L_ + l)) << 8) + (lane << 2)));

  // ---- stream means (joint wave butterflies) ----
  float s0 = st0.x + st0.y + st0.z + st0.w;
  float s1 = st1.x + st1.y + st1.z + st1.w;
  float s2 = st2.x + st2.y + st2.z + st2.w;
  float s3 = st3.x + st3.y + st3.z + st3.w;
  float s4 = st4.x + st4.y + st4.z + st4.w;
  float s5 = st5.x + st5.y + st5.z + st5.w;
  #pragma unroll
  for (int o = 32; o > 0; o >>= 1) {
    s0 += __shfl_down(s0, o, 64); s1 += __shfl_down(s1, o, 64);
    s2 += __shfl_down(s2, o, 64); s3 += __shfl_down(s3, o, 64);
    s4 += __shfl_down(s4, o, 64); s5 += __shfl_down(s5, o, 64);
  }
  if (lane == 0) {
    W[128] = s0 * (1.f / 256.f); W[129] = s1 * (1.f / 256.f);
    W[130] = s2 * (1.f / 256.f); W[131] = s3 * (1.f / 256.f);
    W[132] = s4 * (1.f / 256.f); W[133] = s5 * (1.f / 256.f);
  }
  __syncthreads();  // gin complete (qg staging + summaries) before layer-1 reads

  // ---- MLP layer 1: hm = gelu(gin @ Wf1 + bf1), 134 outputs over 64 lanes ----
  auto dot134 = [&](const float* wrow, const float* gbase) -> float {
    float a = 0.f;
    #pragma unroll
    for (int i = 0; i < 136; i += 4) {
      float4 wv = *(const float4*)(wrow + i);
      float4 gv = *(const float4*)(gbase + i);
      a = fmaf(wv.x, gv.x, a); a = fmaf(wv.y, gv.y, a);
      a = fmaf(wv.z, gv.z, a); a = fmaf(wv.w, gv.w, a);
    }
    return a;
  };
  auto gelu = [](float a) -> float {
    return 0.5f * a * (1.f + erff(a * 0.70710678f));
  };
  {
    float a0 = bf1[lane] + dot134(Wf1T + lane * 136, W);
    float a1 = bf1[lane + 64] + dot134(Wf1T + (lane + 64) * 136, W);
    W[136 + lane] = gelu(a0);
    W[136 + lane + 64] = gelu(a1);
    if (lane < 6) {
      float a2 = bf1[128 + lane] + dot134(Wf1T + (128 + lane) * 136, W);
      W[136 + 128 + lane] = gelu(a2);
    }
    if (lane >= 6 && lane < 8) W[136 + 128 + lane] = 0.f;  // hm pad
  }
  __syncthreads();  // hm complete before layer-2 reads

  // ---- MLP layer 2 + temperature (lanes 0..5) ----
  if (lane < 6) {
    float a = bf2[lane] + dot134(Wf2T + lane * 136, W + 136);
    W[272 + lane] = a / expf(ltm[h]);
  }
  __syncthreads();  // lg complete before softmax
  // ---- softmax + floor (lane 0) ----
  if (lane == 0) {
    float m = W[272];
    #pragma unroll
    for (int j = 1; j < 6; ++j) m = fmaxf(m, W[272 + j]);
    float e[6], ssum = 0.f;
    #pragma unroll
    for (int j = 0; j < 6; ++j) { e[j] = expf(W[272 + j] - m); ssum += e[j]; }
    float inv = 1.f / ssum;
    #pragma unroll
    for (int j = 0; j < 6; ++j) W[280 + j] = e[j] * inv * 0.88f + 0.02f;
  }
  __syncthreads();  // pj complete before fused mix
  // ---- fused mix + RMSNorm ----
  float p0 = W[280], p1 = W[281], p2 = W[282], p3 = W[283], p4 = W[284], p5 = W[285];
  float4 fu;
  fu.x = p0 * st0.x + p1 * st1.x + p2 * st2.x + p3 * st3.x + p4 * st4.x + p5 * st5.x;
  fu.y = p0 * st0.y + p1 * st1.y + p2 * st2.y + p3 * st3.y + p4 * st4.y + p5 * st5.y;
  fu.z = p0 * st0.z + p1 * st1.z + p2 * st2.z + p3 * st3.z + p4 * st4.z + p5 * st5.z;
  fu.w = p0 * st0.w + p1 * st1.w + p2 * st2.w + p3 * st3.w + p4 * st4.w + p5 * st5.w;
  float ssq = fu.x * fu.x + fu.y * fu.y + fu.z * fu.z + fu.w * fu.w;
  #pragma unroll
  for (int o = 32; o > 0; o >>= 1) ssq += __shfl_xor(ssq, o, 64);
  float sc = rsqrtf(ssq * (1.f / 256.f) + 1e-5f);
  float4 ow = *(const float4*)(onw + (lane << 2));
  ushort4 ob;
  ob.x = bf16bits(fu.x * sc * ow.x);
  ob.y = bf16bits(fu.y * sc * ow.y);
  ob.z = bf16bits(fu.z * sc * ow.z);
  ob.w = bf16bits(fu.w * sc * ow.w);
  *(ushort4*)((unsigned short*)obf + vrow) = ob;
}

// ---------------- launch ----------------
extern "C" void kernel_launch(void* const* d_in, const int* in_sizes, int n_in,
                              void* d_out, int out_size, void* d_ws, size_t ws_size,
                              hipStream_t stream) {
  const float* x   = (const float*)d_in[0];
  const float* Wq  = (const float*)d_in[1];
  const float* Wk  = (const float*)d_in[2];
  const float* Wv  = (const float*)d_in[3];
  const float* Wb  = (const float*)d_in[4];
  const float* cqw = (const float*)d_in[5];
  const float* ckw = (const float*)d_in[6];
  const float* cvw = (const float*)d_in[7];
  const float* fw0 = (const float*)d_in[8];
  const float* fw1 = (const float*)d_in[9];
  const float* fw2 = (const float*)d_in[10];
  const float* fw3 = (const float*)d_in[11];
  const float* Wqg = (const float*)d_in[12];
  const float* bqg = (const float*)d_in[13];
  const float* Wf1 = (const float*)d_in[14];
  const float* bf1 = (const float*)d_in[15];
  const float* Wf2 = (const float*)d_in[16];
  const float* bf2 = (const float*)d_in[17];
  const float* ltm = (const float*)d_in[18];
  const float* onw = (const float*)d_in[19];
  const float* Wo  = (const float*)d_in[20];
  float* out = (float*)d_out;
  float* ws = (float*)d_ws;

  // ws footprint identical to the passing round-2/4 layout.
  const size_t BIG = (size_t)BL_ * C_;
  float* qpre = ws;                 // -> qn f32 -> gate_bf after scan
  float* kpre = ws + BIG;           // -> kn f32 -> knT_bf (strided in-place)
  float* vpre = ws + 2 * BIG;       // -> vb -> u f32
  float* qs   = ws + 3 * BIG;       // x_bf early -> conv q -> delta_out
  float* ks   = ws + 4 * BIG;       // conv k (scratch)
  float* vs   = ws + 5 * BIG;       // conv v (FIR/v_direct)
  float* kbw  = ws + 6 * BIG;       // wT bf16 early -> kb -> w_bf -> woT
  float* invb = ws + 7 * BIG;
  float* attb = invb + (size_t)1024 * 1024;   // att_bf (first 2MB of this 4MB region)
  float* beta = attb + (size_t)1024 * 1024;
  float* qg   = beta + (size_t)BL_ * H_;

  __hip_bfloat16* x_bf  = (__hip_bfloat16*)qs;
  __hip_bfloat16* wqT   = (__hip_bfloat16*)kbw;
  __hip_bfloat16* wkT   = wqT + (size_t)1024 * 1024;
  __hip_bfloat16* wvT   = wkT + (size_t)1024 * 1024;
  __hip_bfloat16* wqgT  = wvT + (size_t)1024 * 1024;
  __hip_bfloat16* woT   = (__hip_bfloat16*)kbw;
  __hip_bfloat16* gate_bf = (__hip_bfloat16*)qpre;
  __hip_bfloat16* knT_bf = (__hip_bfloat16*)kpre;
  __hip_bfloat16* w_bf   = (__hip_bfloat16*)kbw;
  __hip_bfloat16* att_bf = (__hip_bfloat16*)attb;
  // small transposed tables in unused tail of attb region (att_bf uses first 524288 floats)
  float* scr   = attb + (size_t)600000;
  float* fw1T  = scr;                  // 3*1024
  float* fw2T  = scr + 3072;           // 7*1024
  float* fw3T  = scr + 10240;          // 15*1024
  float* Wf1T  = scr + 25600;          // 134*136
  float* Wf2T  = scr + 43824;          // 6*136

  dim3 blk(256);
  f32_to_bf16_k<<<dim3(BL_ * D_ / 1024), blk, 0, stream>>>(x, x_bf);
  transpose_bf16<<<dim3(32, 32), blk, 0, stream>>>(Wq, wqT, D_, C_);
  transpose_bf16<<<dim3(32, 32), blk, 0, stream>>>(Wk, wkT, D_, C_);
  transpose_bf16<<<dim3(32, 32), blk, 0, stream>>>(Wv, wvT, D_, C_);
  transpose_bf16<<<dim3(4, 32), blk, 0, stream>>>(Wqg, wqgT, D_, GQP_c);
  small_transpose<<<dim3(16), blk, 0, stream>>>(fw1, fw1T, 1024, 3, 1024);
  small_transpose<<<dim3(32), blk, 0, stream>>>(fw2, fw2T, 1024, 7, 1024);
  small_transpose<<<dim3(64), blk, 0, stream>>>(fw3, fw3T, 1024, 15, 1024);
  small_transpose<<<dim3(72), blk, 0, stream>>>(Wf1, Wf1T, GIN_c, GH_c, 136);
  small_transpose<<<dim3(4), blk, 0, stream>>>(Wf2, Wf2T, GH_c, NS_c, 136);
  gemm_bf16<<<dim3(8, 64), blk, 0, stream>>>(x_bf, wqT, nullptr, qpre, BL_, C_, D_);
  gemm_bf16<<<dim3(8, 64), blk, 0, stream>>>(x_bf, wkT, nullptr, kpre, BL_, C_, D_);
  gemm_bf16<<<dim3(8, 64), blk, 0, stream>>>(x_bf, wvT, nullptr, vpre, BL_, C_, D_);
  gemm_bf16<<<dim3(1, 64), blk, 0, stream>>>(x_bf, wqgT, bqg, qg, BL_, GQP_c, D_);
  beta_kernel<<<dim3(BL_), blk, 0, stream>>>(x, Wb, beta);
  conv_silu<<<dim3(BL_ * C_ / 256), blk, 0, stream>>>(qpre, cqw, qs);
  conv_silu<<<dim3(BL_ * C_ / 256), blk, 0, stream>>>(kpre, ckw, ks);
  conv_silu<<<dim3(BL_ * C_ / 256), blk, 0, stream>>>(vpre, cvw, vs);
  precompute<<<dim3(B_ * H_ * L_), blk, 0, stream>>>(qs, ks, vs, beta, qpre, kpre,
                                                     vpre, kbw);
  inv_attn<<<dim3(1024), blk, 0, stream>>>(qpre, kpre, kbw, invb, att_bf, knT_bf);
  uw_kernel<<<dim3(1024), blk, 0, stream>>>(invb, vpre, kbw, w_bf);
  scan_kernel<<<dim3(128), blk, 0, stream>>>(qpre, w_bf, knT_bf, att_bf, vpre, qs);
  transpose_bf16<<<dim3(32, 32), blk, 0, stream>>>(Wo, woT, C_, D_);
  gate_kernel<<<dim3(BL_), blk, 0, stream>>>(vs, qs, qg, fw0, fw1T, fw2T, fw3T,
                                             Wf1T, Wf2T, bf1, bf2, ltm, onw, gate_bf);
  gemm_bf16<<<dim3(8, 64), blk, 0, stream>>>(gate_bf, woT, nullptr, out, BL_, D_, C_);
}

// Round 7
// 1474.531 us; speedup vs baseline: 2.3344x; 1.0082x over previous
//
#include <hip/hip_runtime.h>
#include <hip/hip_bf16.h>
#include <math.h>

#define B_ 2
#define L_ 4096
#define D_ 1024
#define H_ 4
#define DK_ 256
#define BL_ 8192
#define C_ 1024
#define NCH_ 128
#define GQP_c 128
#define NS_c 6
#define GIN_c 134
#define GH_c 134

typedef __attribute__((ext_vector_type(8))) short short8;
typedef __attribute__((ext_vector_type(4))) float f32x4;

// ---------------- helpers ----------------
__device__ __forceinline__ float block_sum256(float v, float* red) {
  int t = threadIdx.x;
  #pragma unroll
  for (int o = 32; o > 0; o >>= 1) v += __shfl_down(v, o, 64);
  __syncthreads();
  if ((t & 63) == 0) red[t >> 6] = v;
  __syncthreads();
  return red[0] + red[1] + red[2] + red[3];
}

__device__ __forceinline__ unsigned short bf16bits(float f) {
  __hip_bfloat16 h = __float2bfloat16(f);
  return *(unsigned short*)&h;
}

__device__ __forceinline__ float bits2f(unsigned short u) {
  unsigned int x = ((unsigned int)u) << 16;
  return *(float*)&x;
}

__device__ __forceinline__ float4 fma4(float4 a, float4 b, float4 c) {
  return make_float4(fmaf(a.x, b.x, c.x), fmaf(a.y, b.y, c.y),
                     fmaf(a.z, b.z, c.z), fmaf(a.w, b.w, c.w));
}

__device__ __forceinline__ void gload_lds16(const void* g, void* l) {
  __builtin_amdgcn_global_load_lds(
      (const __attribute__((address_space(1))) void*)g,
      (__attribute__((address_space(3))) void*)l, 16, 0, 0);
}

// ---------------- f32 -> bf16 convert ----------------
__global__ __launch_bounds__(256) void f32_to_bf16_k(const float* __restrict__ in,
    __hip_bfloat16* __restrict__ out) {
  size_t i = ((size_t)blockIdx.x * 256 + threadIdx.x) << 2;
  float4 v = *(const float4*)(in + i);
  ushort4 o;
  o.x = bf16bits(v.x); o.y = bf16bits(v.y); o.z = bf16bits(v.z); o.w = bf16bits(v.w);
  *(ushort4*)((unsigned short*)out + i) = o;
}

// ---------------- transpose W(K,N) f32 -> WT(N,K) bf16 ----------------
__global__ __launch_bounds__(256) void transpose_bf16(const float* __restrict__ W,
    __hip_bfloat16* __restrict__ WT, int K, int N) {
  __shared__ float tile[32][33];
  int t = threadIdx.x;
  int r = t >> 3, c4 = (t & 7) << 2;
  int n0 = blockIdx.x << 5, k0 = blockIdx.y << 5;
  float4 v = *(const float4*)(W + (size_t)(k0 + r) * N + n0 + c4);
  tile[r][c4] = v.x; tile[r][c4 + 1] = v.y; tile[r][c4 + 2] = v.z; tile[r][c4 + 3] = v.w;
  __syncthreads();
  ushort4 o;
  o.x = bf16bits(tile[c4][r]);
  o.y = bf16bits(tile[c4 + 1][r]);
  o.z = bf16bits(tile[c4 + 2][r]);
  o.w = bf16bits(tile[c4 + 3][r]);
  *(ushort4*)((unsigned short*)WT + (size_t)(n0 + r) * K + k0 + c4) = o;
}

// ---------------- small f32 transpose with zero-pad: out[c*OS+r] = in[r*Cc+c] ----------------
__global__ __launch_bounds__(256) void small_transpose(const float* __restrict__ in,
    float* __restrict__ out, int R, int Cc, int OS) {
  int total = Cc * OS;
  for (int e = blockIdx.x * 256 + threadIdx.x; e < total; e += gridDim.x * 256) {
    int cIdx = e / OS, r = e - cIdx * OS;
    out[e] = (r < R) ? in[(size_t)r * Cc + cIdx] : 0.f;
  }
}

// ---------------- bf16 MFMA GEMM (m97 structure) ----------------
__global__ __launch_bounds__(256) void gemm_bf16(
    const __hip_bfloat16* __restrict__ A, const __hip_bfloat16* __restrict__ BT,
    const float* __restrict__ bias, float* __restrict__ C, int M, int N, int K) {
  __shared__ __align__(16) __hip_bfloat16 Asm[4096];
  __shared__ __align__(16) __hip_bfloat16 Bsm[4096];
  int tid = threadIdx.x;
  int lane = tid & 63, wave = tid >> 6;
  int wm = wave >> 1, wn = wave & 1;
  int rowBase = blockIdx.y * 128, colBase = blockIdx.x * 128;
  f32x4 acc[4][4];
  #pragma unroll
  for (int i = 0; i < 4; ++i)
    #pragma unroll
    for (int j = 0; j < 4; ++j) acc[i][j] = (f32x4){0.f, 0.f, 0.f, 0.f};

  for (int kt = 0; kt < K; kt += 32) {
    __syncthreads();
    #pragma unroll
    for (int it = 0; it < 2; ++it) {
      int s = tid + (it << 8);
      int T = s >> 6, q = (s >> 4) & 3, m = s & 15;
      const __hip_bfloat16* ga = A + (size_t)(rowBase + T * 16 + m) * K + kt + q * 8;
      gload_lds16(ga, Asm + s * 8);
      const __hip_bfloat16* gb = BT + (size_t)(colBase + T * 16 + m) * K + kt + q * 8;
      gload_lds16(gb, Bsm + s * 8);
    }
    __syncthreads();
    short8 af[4], bfr[4];
    #pragma unroll
    for (int i = 0; i < 4; ++i) {
      af[i]  = *(const short8*)(Asm + ((wm * 4 + i) << 9) + lane * 8);
      bfr[i] = *(const short8*)(Bsm + ((wn * 4 + i) << 9) + lane * 8);
    }
    #pragma unroll
    for (int i = 0; i < 4; ++i)
      #pragma unroll
      for (int j = 0; j < 4; ++j)
        acc[i][j] = __builtin_amdgcn_mfma_f32_16x16x32_bf16(af[i], bfr[j], acc[i][j], 0, 0, 0);
  }
  int r0 = (lane >> 4) * 4, c0 = lane & 15;
  #pragma unroll
  for (int i = 0; i < 4; ++i) {
    int row = rowBase + (wm * 4 + i) * 16 + r0;
    #pragma unroll
    for (int j = 0; j < 4; ++j) {
      int col = colBase + (wn * 4 + j) * 16 + c0;
      float bs = bias ? bias[col] : 0.f;
      #pragma unroll
      for (int r = 0; r < 4; ++r)
        C[(size_t)(row + r) * N + col] = acc[i][j][r] + bs;
    }
  }
}

// ---------------- depthwise causal conv (K=4) + SiLU ----------------
__global__ __launch_bounds__(256) void conv_silu(const float* __restrict__ in,
    const float* __restrict__ w, float* __restrict__ out) {
  int idx = blockIdx.x * 256 + threadIdx.x;
  int c = idx & (C_ - 1);
  int l = (idx >> 10) & (L_ - 1);
  float acc = 0.f;
  #pragma unroll
  for (int j = 0; j < 4; ++j) {
    int ll = l - 3 + j;
    if (ll >= 0) acc += w[(c << 2) + j] * in[idx + ((j - 3) << 10)];
  }
  out[idx] = acc / (1.f + expf(-acc));
}

// ---------------- beta = sigmoid(x @ Wb) ----------------
__global__ __launch_bounds__(256) void beta_kernel(const float* __restrict__ x,
    const float* __restrict__ Wb, float* __restrict__ beta) {
  int row = blockIdx.x;
  int t = threadIdx.x;
  int h = t >> 6, lane = t & 63;
  const float* xr = x + (size_t)row * D_;
  float acc = 0.f;
  for (int k = lane; k < D_; k += 64) acc += xr[k] * Wb[(k << 2) + h];
  #pragma unroll
  for (int o = 32; o > 0; o >>= 1) acc += __shfl_down(acc, o, 64);
  if (lane == 0) beta[(row << 2) + h] = 1.f / (1.f + expf(-acc));
}

// ---------------- l2norm q,k; v*beta; kb; transpose BLHD -> BHLD ----------------
__global__ __launch_bounds__(256) void precompute(const float* __restrict__ q,
    const float* __restrict__ k, const float* __restrict__ v,
    const float* __restrict__ beta,
    float* __restrict__ qn, float* __restrict__ kn,
    float* __restrict__ vb, float* __restrict__ kb) {
  __shared__ float red[4];
  int bid = blockIdx.x;
  int t = threadIdx.x;
  int b = bid >> 14;
  int h = (bid >> 12) & 3;
  int l = bid & (L_ - 1);
  size_t in_off = (((size_t)(b * L_ + l)) << 10) + (h << 8) + t;
  float qv = q[in_off], kv = k[in_off], vv = v[in_off];
  float sq = block_sum256(qv * qv, red);
  float sk = block_sum256(kv * kv, red);
  float rq = rsqrtf(sq + 1e-6f);
  float rk = rsqrtf(sk + 1e-6f);
  float bt = beta[((b * L_ + l) << 2) + h];
  size_t oo = ((size_t)bid << 8) + t;
  float knv = kv * rk;
  qn[oo] = qv * rq;
  kn[oo] = knv;
  vb[oo] = vv * bt;
  kb[oo] = knv * bt;
}

// ---------------- per-chunk: inv (fwd-subst, bf16-rounded) + attn + knT + qn_bf ----------------
// knT_bf occupies first half of each kn f32 chunk slot (ci<<14 shorts);
// qn_bf (bf16 copy of qn chunk, row-major) occupies the second half (+8192 shorts).
__global__ __launch_bounds__(256) void inv_attn(const float* __restrict__ qn,
    const float* kn, const float* __restrict__ kb,
    float* __restrict__ invb, __hip_bfloat16* __restrict__ att_bf,
    __hip_bfloat16* knT_bf) {
  __shared__ float kn_s[32][257];
  __shared__ float inv_s[32][33];
  int ci = blockIdx.x;
  int t = threadIdx.x;
  size_t base = ((size_t)ci) << 13;
  for (int e = t; e < 8192; e += 256) kn_s[e >> 8][e & 255] = kn[base + e];
  __syncthreads();
  {
    unsigned short tmp[32];
    #pragma unroll
    for (int j = 0; j < 32; ++j) tmp[j] = bf16bits(kn_s[j][t]);
    uint4* dst = (uint4*)((unsigned short*)knT_bf + (((size_t)ci) << 14) + (size_t)t * 32);
    const uint4* src = (const uint4*)tmp;
    #pragma unroll
    for (int i = 0; i < 4; ++i) dst[i] = src[i];
  }
  {
    // qn bf16 copy: thread t covers row t>>3, cols (t&7)*32 .. +32
    const float4* qrow = (const float4*)(qn + base + (size_t)(t >> 3) * 256 + ((t & 7) << 5));
    unsigned short tmp[32];
    #pragma unroll
    for (int i = 0; i < 8; ++i) {
      float4 f = qrow[i];
      tmp[i * 4 + 0] = bf16bits(f.x); tmp[i * 4 + 1] = bf16bits(f.y);
      tmp[i * 4 + 2] = bf16bits(f.z); tmp[i * 4 + 3] = bf16bits(f.w);
    }
    uint4* dst = (uint4*)((unsigned short*)knT_bf + (((size_t)ci) << 14) + 8192 + (size_t)t * 32);
    #pragma unroll
    for (int i = 0; i < 4; ++i) dst[i] = ((const uint4*)tmp)[i];
  }
  #pragma unroll
  for (int p = 0; p < 4; ++p) {
    int e = t + (p << 8);
    int i = e >> 5, j = e & 31;
    const float* kbi = kb + base + (i << 8);
    const float* qni = qn + base + (i << 8);
    float am = 0.f, aa = 0.f;
    for (int kk = 0; kk < 256; ++kk) {
      float knv = kn_s[j][kk];
      am += kbi[kk] * knv;
      aa += qni[kk] * knv;
    }
    inv_s[i][j] = (j < i) ? -am : 0.f;
    att_bf[((size_t)ci << 10) + e] = __float2bfloat16((j <= i) ? aa : 0.f);
  }
  __syncthreads();
  for (int i = 1; i < 32; ++i) {
    float upd = 0.f;
    if (t < i) {
      for (int kk = t + 1; kk < i; ++kk) upd += inv_s[i][kk] * inv_s[kk][t];
    }
    __syncthreads();
    if (t < i) inv_s[i][t] += upd;
    __syncthreads();
  }
  #pragma unroll
  for (int p = 0; p < 4; ++p) {
    int e = t + (p << 8);
    int i = e >> 5, j = e & 31;
    float val = inv_s[i][j] + (i == j ? 1.f : 0.f);
    val = __bfloat162float(__float2bfloat16(val));
    invb[((size_t)ci << 10) + e] = val;
  }
}

// ---------------- u = inv@vb (in place f32); w = -(inv@kb) as bf16 in-place ----------------
__global__ __launch_bounds__(256) void uw_kernel(const float* __restrict__ invb,
    float* __restrict__ vb_u, float* kb_w, __hip_bfloat16* w_bf) {
  __shared__ float inv_s[32][33];
  __shared__ float tile[32][260];
  int ci = blockIdx.x, t = threadIdx.x;
  size_t base = ((size_t)ci) << 13;
  for (int e = t; e < 1024; e += 256) inv_s[e >> 5][e & 31] = invb[((size_t)ci << 10) + e];
  for (int ph = 0; ph < 2; ++ph) {
    const float* src = (ph == 0) ? vb_u : kb_w;
    __syncthreads();
    for (int f = t; f < 2048; f += 256) {
      int e = f << 2;
      *(float4*)&tile[e >> 8][e & 255] = *(const float4*)(src + base + e);
    }
    __syncthreads();
    int c4 = (t & 63) << 2;
    int ig = t >> 6;
    float4 acc[8];
    #pragma unroll
    for (int ii = 0; ii < 8; ++ii) acc[ii] = make_float4(0.f, 0.f, 0.f, 0.f);
    for (int j = 0; j < 32; ++j) {
      float4 v4 = *(const float4*)&tile[j][c4];
      #pragma unroll
      for (int ii = 0; ii < 8; ++ii) {
        float iv = inv_s[(ig << 3) + ii][j];
        acc[ii].x += iv * v4.x; acc[ii].y += iv * v4.y;
        acc[ii].z += iv * v4.z; acc[ii].w += iv * v4.w;
      }
    }
    #pragma unroll
    for (int ii = 0; ii < 8; ++ii) {
      int i = (ig << 3) + ii;
      if (ph == 0) {
        *(float4*)(vb_u + base + (i << 8) + c4) = acc[ii];
      } else {
        ushort4 o;
        o.x = bf16bits(-acc[ii].x); o.y = bf16bits(-acc[ii].y);
        o.z = bf16bits(-acc[ii].z); o.w = bf16bits(-acc[ii].w);
        *(ushort4*)((unsigned short*)w_bf + (((size_t)ci) << 14) + (i << 8) + c4) = o;
      }
    }
  }
}

// ---------------- MFMA sequential chunk scan, 2 barriers/step ----------------
// grid = 128: bh = blockIdx&7, cb = blockIdx>>3 (16-col slice).
// Phase A (all 4 waves): w0/w1: ut = u + (-w)@S (rows 0-15/16-31); w2/w3: q@S part of o.
// After B1: w2/w3: o += attn@ut -> store; w0/w1: S(regs,f32) += knT@ut, write bf16 hi/lo image.
// S image + KTb/ATb double-buffered; staging dumped at step end (2 barriers total).
__global__ __launch_bounds__(256) void scan_kernel(
    const __hip_bfloat16* __restrict__ w_bf,
    const __hip_bfloat16* __restrict__ kq_bf,   // per chunk: [0,8192)=knT, [8192,16384)=qn
    const __hip_bfloat16* __restrict__ att_bf,
    const float* __restrict__ u, float* __restrict__ dout) {
  __shared__ __align__(16) unsigned short Wwb[32 * 264];
  __shared__ __align__(16) unsigned short Qb[32 * 264];
  __shared__ __align__(16) unsigned short KTb[2][256 * 40];
  __shared__ __align__(16) unsigned short ATb[2][32 * 40];
  __shared__ __align__(16) unsigned short Shi[2][16 * 264];
  __shared__ __align__(16) unsigned short Slo[2][16 * 264];
  __shared__ __align__(16) float UtT[16 * 36];
  int t = threadIdx.x;
  int bh = blockIdx.x & 7;
  int cb = blockIdx.x >> 3;
  int cbase = cb << 4;
  int lane = t & 63, wave = t >> 6;
  int mlane = lane & 15, quad = lane >> 4;

  uint4 wld[4], qld[4], kld[4]; uint2 ald; float ur[4], urn[4];
  auto load_chunk = [&](int nc) {
    int ci = bh * NCH_ + nc;
    const uint4* wg = (const uint4*)((const unsigned short*)w_bf + ((size_t)ci << 14)) + t * 4;
    const uint4* kg = (const uint4*)((const unsigned short*)kq_bf + ((size_t)ci << 14)) + t * 4;
    const uint4* qg2 = (const uint4*)((const unsigned short*)kq_bf + ((size_t)ci << 14) + 8192) + t * 4;
    #pragma unroll
    for (int i = 0; i < 4; ++i) { wld[i] = wg[i]; kld[i] = kg[i]; qld[i] = qg2[i]; }
    ald = ((const uint2*)((const unsigned short*)att_bf + (((size_t)ci) << 10)))[t];
  };
  auto load_u = [&](int nc, float* dst) {
    if (wave < 2) {
      size_t cbf = ((size_t)(bh * NCH_ + nc)) << 13;
      const float* up = u + cbf + (size_t)(wave * 16 + quad * 4) * 256 + cbase + mlane;
      #pragma unroll
      for (int r = 0; r < 4; ++r) dst[r] = up[r * 256];
    }
  };
  auto dump_chunk = [&](int alt) {
    int r = t >> 3, k0 = (t & 7) << 5;
    uint4* dw = (uint4*)&Wwb[r * 264 + k0];
    uint4* dq = (uint4*)&Qb[r * 264 + k0];
    #pragma unroll
    for (int i = 0; i < 4; ++i) { dw[i] = wld[i]; dq[i] = qld[i]; }
    uint4* dk = (uint4*)&KTb[alt][t * 40];
    #pragma unroll
    for (int i = 0; i < 4; ++i) dk[i] = kld[i];
    *(uint2*)&ATb[alt][(t >> 3) * 40 + ((t & 7) << 2)] = ald;
  };

  for (int e = t; e < 16 * 264; e += 256) { Shi[0][e] = 0; Slo[0][e] = 0; }
  f32x4 accS[8];
  #pragma unroll
  for (int i = 0; i < 8; ++i) accS[i] = (f32x4){0.f, 0.f, 0.f, 0.f};

  load_chunk(0);
  load_u(0, ur);
  dump_chunk(0);
  __syncthreads();

  for (int nc = 0; nc < NCH_; ++nc) {
    int cur = nc & 1, alt = cur ^ 1;
    int nn = nc + 1 < NCH_ ? nc + 1 : NCH_ - 1;
    load_chunk(nn);
    load_u(nn, urn);
    size_t cbf = ((size_t)(bh * NCH_ + nc)) << 13;
    f32x4 c0, c1;
    if (wave < 2) {
      // ---- ut = u + (-w) @ S  (dual independent MFMA chains) ----
      c0 = (f32x4){ur[0], ur[1], ur[2], ur[3]};
      c1 = (f32x4){0.f, 0.f, 0.f, 0.f};
      #pragma unroll
      for (int kt = 0; kt < 8; ++kt) {
        short8 a = *(const short8*)&Wwb[(wave * 16 + mlane) * 264 + kt * 32 + quad * 8];
        short8 shi = *(const short8*)&Shi[cur][mlane * 264 + kt * 32 + quad * 8];
        short8 slo = *(const short8*)&Slo[cur][mlane * 264 + kt * 32 + quad * 8];
        c0 = __builtin_amdgcn_mfma_f32_16x16x32_bf16(a, shi, c0, 0, 0, 0);
        c1 = __builtin_amdgcn_mfma_f32_16x16x32_bf16(a, slo, c1, 0, 0, 0);
      }
      f32x4 s = c0 + c1;
      *(float4*)&UtT[mlane * 36 + wave * 16 + quad * 4] = make_float4(s[0], s[1], s[2], s[3]);
    } else {
      // ---- o partial = qn @ S ----
      int wv = wave - 2;
      c0 = (f32x4){0.f, 0.f, 0.f, 0.f};
      c1 = (f32x4){0.f, 0.f, 0.f, 0.f};
      #pragma unroll
      for (int kt = 0; kt < 8; ++kt) {
        short8 a = *(const short8*)&Qb[(wv * 16 + mlane) * 264 + kt * 32 + quad * 8];
        short8 shi = *(const short8*)&Shi[cur][mlane * 264 + kt * 32 + quad * 8];
        short8 slo = *(const short8*)&Slo[cur][mlane * 264 + kt * 32 + quad * 8];
        c0 = __builtin_amdgcn_mfma_f32_16x16x32_bf16(a, shi, c0, 0, 0, 0);
        c1 = __builtin_amdgcn_mfma_f32_16x16x32_bf16(a, slo, c1, 0, 0, 0);
      }
    }
    __syncthreads();  // B1: UtT visible; all cur Wwb/Qb/S reads done
    short8 but;
    {
      const float* up = &UtT[mlane * 36 + quad * 8];
      #pragma unroll
      for (int j = 0; j < 8; ++j) but[j] = (short)bf16bits(up[j]);
    }
    if (wave >= 2) {
      // ---- o = q@S + attn@ut -> store ----
      int wv = wave - 2;
      short8 aat = *(const short8*)&ATb[cur][(wv * 16 + mlane) * 40 + quad * 8];
      f32x4 o = c0 + c1;
      o = __builtin_amdgcn_mfma_f32_16x16x32_bf16(aat, but, o, 0, 0, 0);
      float* op = dout + cbf + (size_t)(wv * 16 + quad * 4) * 256 + cbase + mlane;
      op[0] = o[0]; op[256] = o[1]; op[512] = o[2]; op[768] = o[3];
    } else {
      // ---- S += knT @ ut (f32 regs), write bf16 hi/lo image to alt ----
      #pragma unroll
      for (int mt = 0; mt < 8; ++mt) {
        int tile = wave * 8 + mt;
        short8 a = *(const short8*)&KTb[cur][(tile * 16 + mlane) * 40 + quad * 8];
        accS[mt] = __builtin_amdgcn_mfma_f32_16x16x32_bf16(a, but, accS[mt], 0, 0, 0);
        unsigned short nh[4], nl[4];
        #pragma unroll
        for (int r = 0; r < 4; ++r) {
          float sv = accS[mt][r];
          unsigned short hb = bf16bits(sv);
          nh[r] = hb;
          nl[r] = bf16bits(sv - bits2f(hb));
        }
        int d0 = tile * 16 + quad * 4;
        *(uint2*)&Shi[alt][mlane * 264 + d0] = *(const uint2*)nh;
        *(uint2*)&Slo[alt][mlane * 264 + d0] = *(const uint2*)nl;
      }
    }
    dump_chunk(alt);
    #pragma unroll
    for (int r = 0; r < 4; ++r) ur[r] = urn[r];
    __syncthreads();  // B2: staging + S image complete
  }
}

// ---------------- gate: wave-per-(b,l,h); 4 barriers at LDS comm points ----------------
__global__ __launch_bounds__(256) void gate_kernel(
    const float* __restrict__ v, const float* __restrict__ delta,
    const float* __restrict__ qg,
    const float* __restrict__ fw0, const float* __restrict__ fw1T,
    const float* __restrict__ fw2T, const float* __restrict__ fw3T,
    const float* __restrict__ Wf1T, const float* __restrict__ Wf2T,
    const float* __restrict__ bf1, const float* __restrict__ bf2,
    const float* __restrict__ ltm, const float* __restrict__ onw,
    __hip_bfloat16* __restrict__ obf) {
  __shared__ __align__(16) float sh[4][296];
  int t = threadIdx.x;
  int wave = t >> 6, lane = t & 63;
  int bl = blockIdx.x;
  int b = bl >> 12, l = bl & (L_ - 1);
  int h = wave;
  float* W = sh[wave];
  int c = (h << 8) + (lane << 2);
  size_t vrow = (((size_t)bl) << 10) + c;

  if (lane < 32)
    *(float4*)&W[lane << 2] = *(const float4*)(qg + (((size_t)bl) << 7) + (lane << 2));
  if (lane == 32) { W[134] = 0.f; W[135] = 0.f; }

  float4 st0, st1, st2, st3, st4, st5;
  st1 = make_float4(0, 0, 0, 0);
  st2 = make_float4(0, 0, 0, 0);
  st3 = make_float4(0, 0, 0, 0);
  #pragma unroll
  for (int j = 0; j < 15; ++j) {
    int ll = l - 14 + j;
    float4 vj = make_float4(0, 0, 0, 0);
    if (ll >= 0) vj = *(const float4*)(v + ((((size_t)(b * L_ + ll)) << 10) + c));
    float4 w3 = *(const float4*)(fw3T + (j << 10) + c);
    st3 = fma4(w3, vj, st3);
    if (j >= 8) {
      float4 w2 = *(const float4*)(fw2T + ((j - 8) << 10) + c);
      st2 = fma4(w2, vj, st2);
    }
    if (j >= 12) {
      float4 w1 = *(const float4*)(fw1T + ((j - 12) << 10) + c);
      st1 = fma4(w1, vj, st1);
    }
    if (j == 14) {
      float4 w0 = *(const float4*)(fw0 + c);
      st0 = make_float4(w0.x * vj.x, w0.y * vj.y, w0.z * vj.z, w0.w * vj.w);
      st5 = vj;
    }
  }
  st4 = *(const float4*)(delta + ((((size_t)((b * H_ + h) * L_ + l)) << 8) + (lane << 2)));

  float s0 = st0.x + st0.y + st0.z + st0.w;
  float s1 = st1.x + st1.y + st1.z + st1.w;
  float s2 = st2.x + st2.y + st2.z + st2.w;
  float s3 = st3.x + st3.y + st3.z + st3.w;
  float s4 = st4.x + st4.y + st4.z + st4.w;
  float s5 = st5.x + st5.y + st5.z + st5.w;
  #pragma unroll
  for (int o = 32; o > 0; o >>= 1) {
    s0 += __shfl_down(s0, o, 64); s1 += __shfl_down(s1, o, 64);
    s2 += __shfl_down(s2, o, 64); s3 += __shfl_down(s3, o, 64);
    s4 += __shfl_down(s4, o, 64); s5 += __shfl_down(s5, o, 64);
  }
  if (lane == 0) {
    W[128] = s0 * (1.f / 256.f); W[129] = s1 * (1.f / 256.f);
    W[130] = s2 * (1.f / 256.f); W[131] = s3 * (1.f / 256.f);
    W[132] = s4 * (1.f / 256.f); W[133] = s5 * (1.f / 256.f);
  }
  __syncthreads();

  auto dot134 = [&](const float* wrow, const float* gbase) -> float {
    float a = 0.f;
    #pragma unroll
    for (int i = 0; i < 136; i += 4) {
      float4 wv = *(const float4*)(wrow + i);
      float4 gv = *(const float4*)(gbase + i);
      a = fmaf(wv.x, gv.x, a); a = fmaf(wv.y, gv.y, a);
      a = fmaf(wv.z, gv.z, a); a = fmaf(wv.w, gv.w, a);
    }
    return a;
  };
  auto gelu = [](float a) -> float {
    return 0.5f * a * (1.f + erff(a * 0.70710678f));
  };
  {
    float a0 = bf1[lane] + dot134(Wf1T + lane * 136, W);
    float a1 = bf1[lane + 64] + dot134(Wf1T + (lane + 64) * 136, W);
    W[136 + lane] = gelu(a0);
    W[136 + lane + 64] = gelu(a1);
    if (lane < 6) {
      float a2 = bf1[128 + lane] + dot134(Wf1T + (128 + lane) * 136, W);
      W[136 + 128 + lane] = gelu(a2);
    }
    if (lane >= 6 && lane < 8) W[136 + 128 + lane] = 0.f;
  }
  __syncthreads();

  if (lane < 6) {
    float a = bf2[lane] + dot134(Wf2T + lane * 136, W + 136);
    W[272 + lane] = a / expf(ltm[h]);
  }
  __syncthreads();
  if (lane == 0) {
    float m = W[272];
    #pragma unroll
    for (int j = 1; j < 6; ++j) m = fmaxf(m, W[272 + j]);
    float e[6], ssum = 0.f;
    #pragma unroll
    for (int j = 0; j < 6; ++j) { e[j] = expf(W[272 + j] - m); ssum += e[j]; }
    float inv = 1.f / ssum;
    #pragma unroll
    for (int j = 0; j < 6; ++j) W[280 + j] = e[j] * inv * 0.88f + 0.02f;
  }
  __syncthreads();
  float p0 = W[280], p1 = W[281], p2 = W[282], p3 = W[283], p4 = W[284], p5 = W[285];
  float4 fu;
  fu.x = p0 * st0.x + p1 * st1.x + p2 * st2.x + p3 * st3.x + p4 * st4.x + p5 * st5.x;
  fu.y = p0 * st0.y + p1 * st1.y + p2 * st2.y + p3 * st3.y + p4 * st4.y + p5 * st5.y;
  fu.z = p0 * st0.z + p1 * st1.z + p2 * st2.z + p3 * st3.z + p4 * st4.z + p5 * st5.z;
  fu.w = p0 * st0.w + p1 * st1.w + p2 * st2.w + p3 * st3.w + p4 * st4.w + p5 * st5.w;
  float ssq = fu.x * fu.x + fu.y * fu.y + fu.z * fu.z + fu.w * fu.w;
  #pragma unroll
  for (int o = 32; o > 0; o >>= 1) ssq += __shfl_xor(ssq, o, 64);
  float sc = rsqrtf(ssq * (1.f / 256.f) + 1e-5f);
  float4 ow = *(const float4*)(onw + (lane << 2));
  ushort4 ob;
  ob.x = bf16bits(fu.x * sc * ow.x);
  ob.y = bf16bits(fu.y * sc * ow.y);
  ob.z = bf16bits(fu.z * sc * ow.z);
  ob.w = bf16bits(fu.w * sc * ow.w);
  *(ushort4*)((unsigned short*)obf + vrow) = ob;
}

// ---------------- launch ----------------
extern "C" void kernel_launch(void* const* d_in, const int* in_sizes, int n_in,
                              void* d_out, int out_size, void* d_ws, size_t ws_size,
                              hipStream_t stream) {
  const float* x   = (const float*)d_in[0];
  const float* Wq  = (const float*)d_in[1];
  const float* Wk  = (const float*)d_in[2];
  const float* Wv  = (const float*)d_in[3];
  const float* Wb  = (const float*)d_in[4];
  const float* cqw = (const float*)d_in[5];
  const float* ckw = (const float*)d_in[6];
  const float* cvw = (const float*)d_in[7];
  const float* fw0 = (const float*)d_in[8];
  const float* fw1 = (const float*)d_in[9];
  const float* fw2 = (const float*)d_in[10];
  const float* fw3 = (const float*)d_in[11];
  const float* Wqg = (const float*)d_in[12];
  const float* bqg = (const float*)d_in[13];
  const float* Wf1 = (const float*)d_in[14];
  const float* bf1 = (const float*)d_in[15];
  const float* Wf2 = (const float*)d_in[16];
  const float* bf2 = (const float*)d_in[17];
  const float* ltm = (const float*)d_in[18];
  const float* onw = (const float*)d_in[19];
  const float* Wo  = (const float*)d_in[20];
  float* out = (float*)d_out;
  float* ws = (float*)d_ws;

  // ws footprint identical to the passing round-2/4/6 layout.
  const size_t BIG = (size_t)BL_ * C_;
  float* qpre = ws;                 // -> qn f32 -> gate_bf after scan
  float* kpre = ws + BIG;           // -> kn f32 -> knT_bf+qn_bf (strided in-place)
  float* vpre = ws + 2 * BIG;       // -> vb -> u f32
  float* qs   = ws + 3 * BIG;       // x_bf early -> conv q -> delta_out
  float* ks   = ws + 4 * BIG;       // conv k (scratch)
  float* vs   = ws + 5 * BIG;       // conv v (FIR/v_direct)
  float* kbw  = ws + 6 * BIG;       // wT bf16 early -> kb -> w_bf -> woT
  float* invb = ws + 7 * BIG;
  float* attb = invb + (size_t)1024 * 1024;
  float* beta = attb + (size_t)1024 * 1024;
  float* qg   = beta + (size_t)BL_ * H_;

  __hip_bfloat16* x_bf  = (__hip_bfloat16*)qs;
  __hip_bfloat16* wqT   = (__hip_bfloat16*)kbw;
  __hip_bfloat16* wkT   = wqT + (size_t)1024 * 1024;
  __hip_bfloat16* wvT   = wkT + (size_t)1024 * 1024;
  __hip_bfloat16* wqgT  = wvT + (size_t)1024 * 1024;
  __hip_bfloat16* woT   = (__hip_bfloat16*)kbw;
  __hip_bfloat16* gate_bf = (__hip_bfloat16*)qpre;
  __hip_bfloat16* knT_bf = (__hip_bfloat16*)kpre;   // + qn_bf in slot second halves
  __hip_bfloat16* w_bf   = (__hip_bfloat16*)kbw;
  __hip_bfloat16* att_bf = (__hip_bfloat16*)attb;
  float* scr   = attb + (size_t)600000;
  float* fw1T  = scr;
  float* fw2T  = scr + 3072;
  float* fw3T  = scr + 10240;
  float* Wf1T  = scr + 25600;
  float* Wf2T  = scr + 43824;

  dim3 blk(256);
  f32_to_bf16_k<<<dim3(BL_ * D_ / 1024), blk, 0, stream>>>(x, x_bf);
  transpose_bf16<<<dim3(32, 32), blk, 0, stream>>>(Wq, wqT, D_, C_);
  transpose_bf16<<<dim3(32, 32), blk, 0, stream>>>(Wk, wkT, D_, C_);
  transpose_bf16<<<dim3(32, 32), blk, 0, stream>>>(Wv, wvT, D_, C_);
  transpose_bf16<<<dim3(4, 32), blk, 0, stream>>>(Wqg, wqgT, D_, GQP_c);
  small_transpose<<<dim3(16), blk, 0, stream>>>(fw1, fw1T, 1024, 3, 1024);
  small_transpose<<<dim3(32), blk, 0, stream>>>(fw2, fw2T, 1024, 7, 1024);
  small_transpose<<<dim3(64), blk, 0, stream>>>(fw3, fw3T, 1024, 15, 1024);
  small_transpose<<<dim3(72), blk, 0, stream>>>(Wf1, Wf1T, GIN_c, GH_c, 136);
  small_transpose<<<dim3(4), blk, 0, stream>>>(Wf2, Wf2T, GH_c, NS_c, 136);
  gemm_bf16<<<dim3(8, 64), blk, 0, stream>>>(x_bf, wqT, nullptr, qpre, BL_, C_, D_);
  gemm_bf16<<<dim3(8, 64), blk, 0, stream>>>(x_bf, wkT, nullptr, kpre, BL_, C_, D_);
  gemm_bf16<<<dim3(8, 64), blk, 0, stream>>>(x_bf, wvT, nullptr, vpre, BL_, C_, D_);
  gemm_bf16<<<dim3(1, 64), blk, 0, stream>>>(x_bf, wqgT, bqg, qg, BL_, GQP_c, D_);
  beta_kernel<<<dim3(BL_), blk, 0, stream>>>(x, Wb, beta);
  conv_silu<<<dim3(BL_ * C_ / 256), blk, 0, stream>>>(qpre, cqw, qs);
  conv_silu<<<dim3(BL_ * C_ / 256), blk, 0, stream>>>(kpre, ckw, ks);
  conv_silu<<<dim3(BL_ * C_ / 256), blk, 0, stream>>>(vpre, cvw, vs);
  precompute<<<dim3(B_ * H_ * L_), blk, 0, stream>>>(qs, ks, vs, beta, qpre, kpre,
                                                     vpre, kbw);
  inv_attn<<<dim3(1024), blk, 0, stream>>>(qpre, kpre, kbw, invb, att_bf, knT_bf);
  uw_kernel<<<dim3(1024), blk, 0, stream>>>(invb, vpre, kbw, w_bf);
  scan_kernel<<<dim3(128), blk, 0, stream>>>(w_bf, knT_bf, att_bf, vpre, qs);
  transpose_bf16<<<dim3(32, 32), blk, 0, stream>>>(Wo, woT, C_, D_);
  gate_kernel<<<dim3(BL_), blk, 0, stream>>>(vs, qs, qg, fw0, fw1T, fw2T, fw3T,
                                             Wf1T, Wf2T, bf1, bf2, ltm, onw, gate_bf);
  gemm_bf16<<<dim3(8, 64), blk, 0, stream>>>(gate_bf, woT, nullptr, out, BL_, D_, C_);
}